// Round 1
// baseline (3769.378 us; speedup 1.0000x reference)
//
#include <hip/hip_runtime.h>
#include <math.h>

#define NNODES 32768
#define NLIG   1024
#define KAT    32
#define KNN    8
#define NEDGES (NNODES*KNN)
#define HID    128
#define TF     16
#define NG     20
#define MID    292     // 2*HID + 36
#define OUTF   64

__device__ __forceinline__ float siluf(float v) {
    return __fdividef(v, 1.0f + __expf(-v));
}
__device__ __forceinline__ float sigf(float v) {
    return __fdividef(1.0f, 1.0f + __expf(-v));
}

// ---------------------------------------------------------------- embed
__global__ __launch_bounds__(HID) void embed_k(
    const float* __restrict__ h, const int* __restrict__ t,
    const float* __restrict__ temb, const float* __restrict__ Win,
    const float* __restrict__ bin, float* __restrict__ hh)
{
    __shared__ float sIn[2*TF];
    const int node = blockIdx.x, tid = threadIdx.x;
    if (tid < TF)        sIn[tid] = h[node*TF + tid];
    else if (tid < 2*TF) sIn[tid] = temb[t[node]*TF + (tid-TF)];
    __syncthreads();
    float acc = bin[tid];
    #pragma unroll
    for (int i = 0; i < 2*TF; ++i)
        acc = fmaf(sIn[i], Win[i*HID + tid], acc);
    hh[node*HID + tid] = acc;
}

// ---------------------------------------------------------------- edge model
// one block per node; its 8 edges are contiguous (row = repeat(arange(N),8))
__global__ __launch_bounds__(256) void edge_k(
    const float* __restrict__ hh, const float* __restrict__ x,
    const int* __restrict__ erow, const int* __restrict__ ecol,
    const int* __restrict__ tbond, const float* __restrict__ temb,
    const float* __restrict__ We1, const float* __restrict__ be1,
    const float* __restrict__ g1, const float* __restrict__ bt1,
    const float* __restrict__ We2, const float* __restrict__ be2,
    const float* __restrict__ Watt, const float* __restrict__ batt,
    float* __restrict__ agg)
{
    __shared__ float sIn[KNN][MID];    // edge MLP input, later reused for post-LN acts
    __shared__ float sMid[KNN][HID];   // raw GEMM1 output
    __shared__ float sAtt[4][4];
    __shared__ float sAgg[2][HID];
    __shared__ int   sRow[KNN], sCol[KNN], sTB[KNN];
    __shared__ float sDist[KNN];

    const int node = blockIdx.x, tid = threadIdx.x;

    if (tid < KNN) {
        int ge = node*KNN + tid;
        int r = erow[ge], c = ecol[ge];
        sRow[tid] = r; sCol[tid] = c;
        float dx = x[3*r+0]-x[3*c+0];
        float dy = x[3*r+1]-x[3*c+1];
        float dz = x[3*r+2]-x[3*c+2];
        sDist[tid] = fminf(sqrtf(dx*dx+dy*dy+dz*dz), 4.0f);
        int sbi = r*(KAT-1) + c - (r/KAT)*KAT - (r < c ? 1 : 0);
        sTB[tid] = tbond[sbi];
    }
    __syncthreads();

    // build [8][292] input: [hh[row] | hh[col] | temb[t_bond] | smear(20)]
    for (int idx = tid; idx < KNN*MID; idx += 256) {
        int e = idx / MID, i = idx - e*MID;
        float v;
        if (i < HID)            v = hh[sRow[e]*HID + i];
        else if (i < 2*HID)     v = hh[sCol[e]*HID + (i-HID)];
        else if (i < 2*HID+TF)  v = temb[sTB[e]*TF + (i-2*HID)];
        else {
            int g = i - (2*HID+TF);
            const float C = 0.12220674183617694f;   // log2(5)/19
            float og = exp2f(C*(float)g) - 1.0f;    // offset[g] = 5^(g/19)-1
            int gm = (g > 0) ? g : 1;
            float d = exp2f(C*(float)gm) - exp2f(C*(float)(gm-1));
            float coeff = -0.5f / (d*d);
            float dd = sDist[e] - og;
            v = __expf(coeff*dd*dd);
        }
        sIn[e][i] = v;
    }
    __syncthreads();

    const int o = tid & (HID-1);      // output column
    const int epair = tid >> 7;       // which 4-edge group
    const int e0 = epair*4;

    // GEMM1: [8 x 292] @ [292 x 128]
    float a0, a1, a2, a3;
    a0 = a1 = a2 = a3 = be1[o];
    {
        const float* w = We1 + o;
        #pragma unroll 4
        for (int i = 0; i < MID; ++i) {
            float wv = w[(size_t)i*HID];
            a0 = fmaf(sIn[e0+0][i], wv, a0);
            a1 = fmaf(sIn[e0+1][i], wv, a1);
            a2 = fmaf(sIn[e0+2][i], wv, a2);
            a3 = fmaf(sIn[e0+3][i], wv, a3);
        }
    }
    sMid[e0+0][o] = a0; sMid[e0+1][o] = a1;
    sMid[e0+2][o] = a2; sMid[e0+3][o] = a3;
    __syncthreads();

    // LayerNorm + affine + SiLU per edge (32 lanes per edge, 4 cols each)
    {
        const int grp = tid >> 5, ln = tid & 31;
        float v0 = sMid[grp][ln],    v1 = sMid[grp][ln+32],
              v2 = sMid[grp][ln+64], v3 = sMid[grp][ln+96];
        float s = v0+v1+v2+v3;
        float q = v0*v0+v1*v1+v2*v2+v3*v3;
        #pragma unroll
        for (int m = 16; m >= 1; m >>= 1) { s += __shfl_xor(s, m); q += __shfl_xor(q, m); }
        float mu  = s * (1.0f/HID);
        float var = q * (1.0f/HID) - mu*mu;
        float inv = rsqrtf(var + 1e-5f);
        float y0 = siluf(fmaf((v0-mu)*inv, g1[ln],    bt1[ln]));
        float y1 = siluf(fmaf((v1-mu)*inv, g1[ln+32], bt1[ln+32]));
        float y2 = siluf(fmaf((v2-mu)*inv, g1[ln+64], bt1[ln+64]));
        float y3 = siluf(fmaf((v3-mu)*inv, g1[ln+96], bt1[ln+96]));
        sIn[grp][ln]    = y0; sIn[grp][ln+32] = y1;
        sIn[grp][ln+64] = y2; sIn[grp][ln+96] = y3;
    }
    __syncthreads();

    // GEMM2: [8 x 128] @ [128 x 128], + SiLU
    float c0, c1, c2, c3;
    c0 = c1 = c2 = c3 = be2[o];
    {
        const float* w = We2 + o;
        #pragma unroll 4
        for (int i = 0; i < HID; ++i) {
            float wv = w[(size_t)i*HID];
            c0 = fmaf(sIn[e0+0][i], wv, c0);
            c1 = fmaf(sIn[e0+1][i], wv, c1);
            c2 = fmaf(sIn[e0+2][i], wv, c2);
            c3 = fmaf(sIn[e0+3][i], wv, c3);
        }
    }
    float m0 = siluf(c0), m1 = siluf(c1), m2 = siluf(c2), m3 = siluf(c3);

    // attention gate: sigmoid(mij @ Watt + batt)
    float wa = Watt[o];
    float p0 = m0*wa, p1 = m1*wa, p2 = m2*wa, p3 = m3*wa;
    #pragma unroll
    for (int m = 1; m < 64; m <<= 1) {
        p0 += __shfl_xor(p0, m); p1 += __shfl_xor(p1, m);
        p2 += __shfl_xor(p2, m); p3 += __shfl_xor(p3, m);
    }
    const int wave = tid >> 6;
    if ((tid & 63) == 0) {
        sAtt[wave][0] = p0; sAtt[wave][1] = p1;
        sAtt[wave][2] = p2; sAtt[wave][3] = p3;
    }
    __syncthreads();
    const float ba = batt[0];
    float t0 = sigf(sAtt[2*epair][0] + sAtt[2*epair+1][0] + ba);
    float t1 = sigf(sAtt[2*epair][1] + sAtt[2*epair+1][1] + ba);
    float t2 = sigf(sAtt[2*epair][2] + sAtt[2*epair+1][2] + ba);
    float t3 = sigf(sAtt[2*epair][3] + sAtt[2*epair+1][3] + ba);

    // gated sum over this thread's 4 edges, then combine the two halves
    sAgg[epair][o] = m0*t0 + m1*t1 + m2*t2 + m3*t3;
    __syncthreads();
    if (tid < HID)
        agg[node*HID + tid] = (sAgg[0][tid] + sAgg[1][tid]) * 0.2f;  // /NORM_FACTOR
}

// ---------------------------------------------------------------- node model
__global__ __launch_bounds__(HID) void node_k(
    float* __restrict__ hh, const float* __restrict__ agg,
    const float* __restrict__ Wn1, const float* __restrict__ bn1,
    const float* __restrict__ g2, const float* __restrict__ bt2,
    const float* __restrict__ Wn2, const float* __restrict__ bn2)
{
    __shared__ float sX[2*HID];
    __shared__ float sY[HID];
    __shared__ float sS[2], sQ[2];
    const int node = blockIdx.x, tid = threadIdx.x;
    sX[tid]       = hh[node*HID + tid];
    sX[HID + tid] = agg[node*HID + tid];
    __syncthreads();

    float acc = bn1[tid];
    {
        const float* w = Wn1 + tid;
        #pragma unroll 4
        for (int i = 0; i < 2*HID; ++i)
            acc = fmaf(sX[i], w[(size_t)i*HID], acc);
    }
    float s = acc, q = acc*acc;
    #pragma unroll
    for (int m = 1; m < 64; m <<= 1) { s += __shfl_xor(s, m); q += __shfl_xor(q, m); }
    const int wave = tid >> 6;
    if ((tid & 63) == 0) { sS[wave] = s; sQ[wave] = q; }
    __syncthreads();
    float mu  = (sS[0] + sS[1]) * (1.0f/HID);
    float var = (sQ[0] + sQ[1]) * (1.0f/HID) - mu*mu;
    float inv = rsqrtf(var + 1e-5f);
    float y = siluf(fmaf((acc-mu)*inv, g2[tid], bt2[tid]));
    sY[tid] = y;
    __syncthreads();

    float acc2 = bn2[tid];
    {
        const float* w = Wn2 + tid;
        #pragma unroll 4
        for (int i = 0; i < HID; ++i)
            acc2 = fmaf(sY[i], w[(size_t)i*HID], acc2);
    }
    hh[node*HID + tid] = sX[tid] + acc2;   // residual
}

// ---------------------------------------------------------------- output head
// pooling is a mean over 32 atoms; it commutes with the linear layers:
// out[lig] = (mean_a hh[a]) @ W_oe @ W_f + b_oe @ W_f + b_f
__global__ __launch_bounds__(HID) void out_k(
    const float* __restrict__ hh, const float* __restrict__ Woe,
    const float* __restrict__ boe, const float* __restrict__ Wf,
    const float* __restrict__ bf, float* __restrict__ out)
{
    __shared__ float sH[HID];
    const int lig = blockIdx.x, tid = threadIdx.x;
    float s = 0.0f;
    const float* base = hh + (size_t)lig*KAT*HID + tid;
    #pragma unroll 8
    for (int a = 0; a < KAT; ++a) s += base[a*HID];
    sH[tid] = s * (1.0f/KAT);
    __syncthreads();

    float contrib = 0.0f;
    if (tid < OUTF) {
        float p = boe[tid];
        #pragma unroll 4
        for (int i = 0; i < HID; ++i)
            p = fmaf(sH[i], Woe[i*OUTF + tid], p);
        contrib = p * Wf[tid];
    }
    #pragma unroll
    for (int m = 1; m < 64; m <<= 1) contrib += __shfl_xor(contrib, m);
    if (tid == 0) out[lig] = contrib + bf[0];
}

// ---------------------------------------------------------------- launch
extern "C" void kernel_launch(void* const* d_in, const int* in_sizes, int n_in,
                              void* d_out, int out_size, void* d_ws, size_t ws_size,
                              hipStream_t stream)
{
    (void)in_sizes; (void)n_in; (void)out_size; (void)ws_size;
    const float* x    = (const float*)d_in[0];
    const float* h    = (const float*)d_in[1];
    const int*   t    = (const int*)d_in[2];
    const int*   edges= (const int*)d_in[3];
    const int*   tb   = (const int*)d_in[4];
    // d_in[5] batch_ligand, d_in[6] K, d_in[7] num_ligands: structure hardcoded
    const float* temb = (const float*)d_in[8];
    const float* Win  = (const float*)d_in[9];
    const float* bin  = (const float*)d_in[10];
    const float* We1  = (const float*)d_in[11];
    const float* be1  = (const float*)d_in[12];
    const float* g1   = (const float*)d_in[13];
    const float* bt1  = (const float*)d_in[14];
    const float* We2  = (const float*)d_in[15];
    const float* be2  = (const float*)d_in[16];
    const float* Watt = (const float*)d_in[17];
    const float* batt = (const float*)d_in[18];
    const float* Wn1  = (const float*)d_in[19];
    const float* bn1  = (const float*)d_in[20];
    const float* g2   = (const float*)d_in[21];
    const float* bt2  = (const float*)d_in[22];
    const float* Wn2  = (const float*)d_in[23];
    const float* bn2  = (const float*)d_in[24];
    const float* Woe  = (const float*)d_in[25];
    const float* boe  = (const float*)d_in[26];
    const float* Wf   = (const float*)d_in[27];
    const float* bf   = (const float*)d_in[28];
    float* out = (float*)d_out;

    float* hh  = (float*)d_ws;                       // [N,128] 16 MB
    float* agg = hh + (size_t)NNODES*HID;            // [N,128] 16 MB

    embed_k<<<NNODES, HID, 0, stream>>>(h, t, temb, Win, bin, hh);
    for (int l = 0; l < 4; ++l) {
        edge_k<<<NNODES, 256, 0, stream>>>(hh, x, edges, edges + NEDGES, tb, temb,
            We1 + (size_t)l*MID*HID, be1 + l*HID, g1 + l*HID, bt1 + l*HID,
            We2 + (size_t)l*HID*HID, be2 + l*HID,
            Watt + l*HID, batt + l, agg);
        node_k<<<NNODES, HID, 0, stream>>>(hh, agg,
            Wn1 + (size_t)l*2*HID*HID, bn1 + l*HID, g2 + l*HID, bt2 + l*HID,
            Wn2 + (size_t)l*HID*HID, bn2 + l*HID);
    }
    out_k<<<NLIG, HID, 0, stream>>>(hh, Woe, boe, Wf, bf, out);
}

// Round 2
// 2185.948 us; speedup vs baseline: 1.7244x; 1.7244x over previous
//
#include <hip/hip_runtime.h>
#include <math.h>

#define NNODES 32768
#define NLIG   1024
#define KAT    32
#define KNN    8
#define NEDGES (NNODES*KNN)
#define HID    128
#define TF     16
#define NG     20
#define OUTF   64

#define NPB    4            // nodes per edge-block
#define EPB    32           // edges per edge-block (NPB*KNN)
#define KE     164          // edge GEMM1 K after hoisting hh[row] part
#define ASTR   168          // sAct row stride (floats), 16B-aligned

#define NPBN   8            // nodes per node-block

__device__ __forceinline__ float siluf(float v) {
    return __fdividef(v, 1.0f + __expf(-v));
}
__device__ __forceinline__ float sigf(float v) {
    return __fdividef(1.0f, 1.0f + __expf(-v));
}

// ---------------------------------------------------------------- embed
__global__ __launch_bounds__(HID) void embed_k(
    const float* __restrict__ h, const int* __restrict__ t,
    const float* __restrict__ temb, const float* __restrict__ Win,
    const float* __restrict__ bin, float* __restrict__ hh)
{
    __shared__ float sIn[2*TF];
    const int node = blockIdx.x, tid = threadIdx.x;
    if (tid < TF)        sIn[tid] = h[node*TF + tid];
    else if (tid < 2*TF) sIn[tid] = temb[t[node]*TF + (tid-TF)];
    __syncthreads();
    float acc = bin[tid];
    #pragma unroll
    for (int i = 0; i < 2*TF; ++i)
        acc = fmaf(sIn[i], Win[i*HID + tid], acc);
    hh[node*HID + tid] = acc;
}

// ---------------------------------------------------------------- edge model
// 4 nodes / block, 32 edges. Edges of node n are [8n, 8n+8) (row=repeat(arange,8)).
// GEMM1 split: m = hh[row]@Wa + [hh[col]|temb|smear]@Wb + be1, Wa=We1[0:128], Wb=We1[128:292].
__global__ __launch_bounds__(256) void edge_k(
    const float* __restrict__ hh, const float* __restrict__ x,
    const int* __restrict__ ecol, const int* __restrict__ tbond,
    const float* __restrict__ temb,
    const float* __restrict__ We1, const float* __restrict__ be1,
    const float* __restrict__ g1, const float* __restrict__ bt1,
    const float* __restrict__ We2, const float* __restrict__ be2,
    const float* __restrict__ Watt, const float* __restrict__ batt,
    float* __restrict__ agg)
{
    __shared__ float sAct[EPB][ASTR];   // [hh[col](128) | temb(16) | smear(20)]; later holds mid/LN acts in cols 0..127
    __shared__ float sHH[NPB][HID];     // the 4 nodes' own hh rows
    __shared__ int   sCol[EPB];
    __shared__ int   sTB[EPB];
    __shared__ float sRed[4][16];
    __shared__ float sAttv[EPB];

    const int tid   = threadIdx.x;
    const int node0 = blockIdx.x * NPB;
    const int o     = tid & (HID-1);
    const int half  = tid >> 7;
    const int ebase = half * 16;

    // ---- phase A: per-edge meta (col, t_bond, smear) --------------------
    if (tid < EPB) {
        const int e = tid;
        const int r = node0 + (e >> 3);
        const int c = ecol[node0*KNN + e];
        sCol[e] = c;
        float dx = x[3*r+0]-x[3*c+0];
        float dy = x[3*r+1]-x[3*c+1];
        float dz = x[3*r+2]-x[3*c+2];
        float dist = fminf(sqrtf(dx*dx+dy*dy+dz*dz), 4.0f);
        int sbi = r*(KAT-1) + c - (r/KAT)*KAT - (r < c ? 1 : 0);
        sTB[e] = tbond[sbi];
        const float C = 0.12220674183617694f;   // log2(5)/19
        #pragma unroll
        for (int g = 0; g < NG; ++g) {
            float og = exp2f(C*(float)g) - 1.0f;
            int gm = (g > 0) ? g : 1;
            float d = exp2f(C*(float)gm) - exp2f(C*(float)(gm-1));
            float coeff = -0.5f / (d*d);
            float dd = dist - og;
            sAct[e][144 + g] = __expf(coeff*dd*dd);
        }
    }
    __syncthreads();

    // ---- phase B: stage activations ------------------------------------
    // hh[col]: 32 edges x 128 floats = 1024 float4
    for (int idx = tid; idx < EPB*32; idx += 256) {
        int e = idx >> 5, k4 = idx & 31;
        *(float4*)&sAct[e][k4*4] =
            *(const float4*)&hh[(size_t)sCol[e]*HID + k4*4];
    }
    // temb[t_bond]: 32 x 16
    for (int idx = tid; idx < EPB*TF; idx += 256) {
        int e = idx >> 4, f = idx & 15;
        sAct[e][HID + f] = temb[sTB[e]*TF + f];
    }
    // own hh rows: 4 x 128 = 128 float4
    if (tid < NPB*32) {
        int n = tid >> 5, k4 = tid & 31;
        *(float4*)&sHH[n][k4*4] =
            *(const float4*)&hh[(size_t)(node0+n)*HID + k4*4];
    }
    __syncthreads();

    // ---- phase C: per-node hoisted term P = hh[node] @ Wa --------------
    float pn0 = 0.0f, pn1 = 0.0f;
    {
        const float* wp = We1 + o;
        const float4* h0 = (const float4*)sHH[half*2+0];
        const float4* h1 = (const float4*)sHH[half*2+1];
        #pragma unroll 8
        for (int k4 = 0; k4 < 32; ++k4) {
            float w0 = wp[0*HID], w1 = wp[1*HID], w2 = wp[2*HID], w3 = wp[3*HID];
            wp += 4*HID;
            float4 a = h0[k4], b = h1[k4];
            pn0 = fmaf(a.x,w0,pn0); pn0 = fmaf(a.y,w1,pn0);
            pn0 = fmaf(a.z,w2,pn0); pn0 = fmaf(a.w,w3,pn0);
            pn1 = fmaf(b.x,w0,pn1); pn1 = fmaf(b.y,w1,pn1);
            pn1 = fmaf(b.z,w2,pn1); pn1 = fmaf(b.w,w3,pn1);
        }
    }

    // ---- phase D: edge GEMM1 (K=164), 16 edges x 1 col per thread ------
    float acc[16];
    {
        const float bias1 = be1[o];
        #pragma unroll
        for (int j = 0; j < 16; ++j) acc[j] = (j < 8 ? pn0 : pn1) + bias1;
        const float* wp = We1 + (size_t)HID*HID + o;
        const char*  ab = (const char*)&sAct[ebase][0];
        for (int k4 = 0; k4 < KE/4; ++k4) {
            float w0 = wp[0*HID], w1 = wp[1*HID], w2 = wp[2*HID], w3 = wp[3*HID];
            wp += 4*HID;
            #pragma unroll
            for (int j = 0; j < 16; ++j) {
                float4 a = *(const float4*)(ab + (size_t)j*ASTR*4 + (size_t)k4*16);
                acc[j] = fmaf(a.x,w0,acc[j]); acc[j] = fmaf(a.y,w1,acc[j]);
                acc[j] = fmaf(a.z,w2,acc[j]); acc[j] = fmaf(a.w,w3,acc[j]);
            }
        }
    }
    __syncthreads();            // sAct reads done; safe to overwrite cols 0..127
    #pragma unroll
    for (int j = 0; j < 16; ++j) sAct[ebase+j][o] = acc[j];
    __syncthreads();

    // ---- phase E: in-place LayerNorm + SiLU (8 lanes per edge) ---------
    {
        const int e  = tid >> 3;
        const int c0 = (tid & 7) * 16;
        float4 v0 = *(const float4*)&sAct[e][c0+0];
        float4 v1 = *(const float4*)&sAct[e][c0+4];
        float4 v2 = *(const float4*)&sAct[e][c0+8];
        float4 v3 = *(const float4*)&sAct[e][c0+12];
        float s = v0.x+v0.y+v0.z+v0.w + v1.x+v1.y+v1.z+v1.w
                + v2.x+v2.y+v2.z+v2.w + v3.x+v3.y+v3.z+v3.w;
        float q = v0.x*v0.x+v0.y*v0.y+v0.z*v0.z+v0.w*v0.w
                + v1.x*v1.x+v1.y*v1.y+v1.z*v1.z+v1.w*v1.w
                + v2.x*v2.x+v2.y*v2.y+v2.z*v2.z+v2.w*v2.w
                + v3.x*v3.x+v3.y*v3.y+v3.z*v3.z+v3.w*v3.w;
        #pragma unroll
        for (int m = 4; m >= 1; m >>= 1) { s += __shfl_xor(s, m); q += __shfl_xor(q, m); }
        float mu  = s * (1.0f/HID);
        float var = q * (1.0f/HID) - mu*mu;
        float inv = rsqrtf(var + 1e-5f);
        float4 G0 = *(const float4*)&g1[c0+0],  G1 = *(const float4*)&g1[c0+4];
        float4 G2 = *(const float4*)&g1[c0+8],  G3 = *(const float4*)&g1[c0+12];
        float4 B0 = *(const float4*)&bt1[c0+0], B1 = *(const float4*)&bt1[c0+4];
        float4 B2 = *(const float4*)&bt1[c0+8], B3 = *(const float4*)&bt1[c0+12];
        v0.x = siluf(fmaf((v0.x-mu)*inv, G0.x, B0.x)); v0.y = siluf(fmaf((v0.y-mu)*inv, G0.y, B0.y));
        v0.z = siluf(fmaf((v0.z-mu)*inv, G0.z, B0.z)); v0.w = siluf(fmaf((v0.w-mu)*inv, G0.w, B0.w));
        v1.x = siluf(fmaf((v1.x-mu)*inv, G1.x, B1.x)); v1.y = siluf(fmaf((v1.y-mu)*inv, G1.y, B1.y));
        v1.z = siluf(fmaf((v1.z-mu)*inv, G1.z, B1.z)); v1.w = siluf(fmaf((v1.w-mu)*inv, G1.w, B1.w));
        v2.x = siluf(fmaf((v2.x-mu)*inv, G2.x, B2.x)); v2.y = siluf(fmaf((v2.y-mu)*inv, G2.y, B2.y));
        v2.z = siluf(fmaf((v2.z-mu)*inv, G2.z, B2.z)); v2.w = siluf(fmaf((v2.w-mu)*inv, G2.w, B2.w));
        v3.x = siluf(fmaf((v3.x-mu)*inv, G3.x, B3.x)); v3.y = siluf(fmaf((v3.y-mu)*inv, G3.y, B3.y));
        v3.z = siluf(fmaf((v3.z-mu)*inv, G3.z, B3.z)); v3.w = siluf(fmaf((v3.w-mu)*inv, G3.w, B3.w));
        *(float4*)&sAct[e][c0+0]  = v0;  *(float4*)&sAct[e][c0+4]  = v1;
        *(float4*)&sAct[e][c0+8]  = v2;  *(float4*)&sAct[e][c0+12] = v3;
    }
    __syncthreads();

    // ---- phase F: GEMM2 (K=128) + SiLU ---------------------------------
    float m_[16];
    {
        float acc2[16];
        const float bias2 = be2[o];
        #pragma unroll
        for (int j = 0; j < 16; ++j) acc2[j] = bias2;
        const float* wp = We2 + o;
        const char*  ab = (const char*)&sAct[ebase][0];
        for (int k4 = 0; k4 < HID/4; ++k4) {
            float w0 = wp[0*HID], w1 = wp[1*HID], w2 = wp[2*HID], w3 = wp[3*HID];
            wp += 4*HID;
            #pragma unroll
            for (int j = 0; j < 16; ++j) {
                float4 a = *(const float4*)(ab + (size_t)j*ASTR*4 + (size_t)k4*16);
                acc2[j] = fmaf(a.x,w0,acc2[j]); acc2[j] = fmaf(a.y,w1,acc2[j]);
                acc2[j] = fmaf(a.z,w2,acc2[j]); acc2[j] = fmaf(a.w,w3,acc2[j]);
            }
        }
        #pragma unroll
        for (int j = 0; j < 16; ++j) m_[j] = siluf(acc2[j]);
    }

    // ---- phase G: attention gate ---------------------------------------
    {
        const float wa = Watt[o];
        float p[16];
        #pragma unroll
        for (int j = 0; j < 16; ++j) p[j] = m_[j]*wa;
        #pragma unroll
        for (int msk = 1; msk < 64; msk <<= 1) {
            #pragma unroll
            for (int j = 0; j < 16; ++j) p[j] += __shfl_xor(p[j], msk);
        }
        const int wv = tid >> 6;
        if ((tid & 63) == 0) {
            #pragma unroll
            for (int j = 0; j < 16; ++j) sRed[wv][j] = p[j];
        }
    }
    __syncthreads();
    if (tid < EPB) {
        const int h2 = tid >> 4, j = tid & 15;
        sAttv[tid] = sigf(sRed[h2*2][j] + sRed[h2*2+1][j] + batt[0]);
    }
    __syncthreads();

    // ---- phase H: gated aggregate --------------------------------------
    {
        float s0 = 0.0f, s1 = 0.0f;
        #pragma unroll
        for (int j = 0; j < 8; ++j)  s0 += m_[j]   * sAttv[ebase+j];
        #pragma unroll
        for (int j = 0; j < 8; ++j)  s1 += m_[8+j] * sAttv[ebase+8+j];
        agg[(size_t)(node0 + half*2 + 0)*HID + o] = s0 * 0.2f;
        agg[(size_t)(node0 + half*2 + 1)*HID + o] = s1 * 0.2f;
    }
}

// ---------------------------------------------------------------- node model
// 8 nodes / block, 256 threads; thread = (col o, 4-node group half)
__global__ __launch_bounds__(256) void node_k(
    float* __restrict__ hh, const float* __restrict__ agg,
    const float* __restrict__ Wn1, const float* __restrict__ bn1,
    const float* __restrict__ g2, const float* __restrict__ bt2,
    const float* __restrict__ Wn2, const float* __restrict__ bn2)
{
    __shared__ float sX[NPBN][2*HID];
    __shared__ float sY[NPBN][HID];
    __shared__ float sS[4][4], sQ[4][4];

    const int tid   = threadIdx.x;
    const int node0 = blockIdx.x * NPBN;
    const int o     = tid & (HID-1);
    const int half  = tid >> 7;

    // stage [hh | agg] per node: 8 x 256 floats = 512 float4
    for (int idx = tid; idx < NPBN*64; idx += 256) {
        int n = idx >> 6, k4 = idx & 63;
        float4 v;
        if (k4 < 32) v = *(const float4*)&hh [(size_t)(node0+n)*HID + k4*4];
        else         v = *(const float4*)&agg[(size_t)(node0+n)*HID + (k4-32)*4];
        *(float4*)&sX[n][k4*4] = v;
    }
    __syncthreads();

    float acc[4];
    {
        const float b1 = bn1[o];
        #pragma unroll
        for (int b = 0; b < 4; ++b) acc[b] = b1;
        const float* wp = Wn1 + o;
        const char*  xb = (const char*)&sX[half*4][0];
        for (int k4 = 0; k4 < (2*HID)/4; ++k4) {
            float w0 = wp[0*HID], w1 = wp[1*HID], w2 = wp[2*HID], w3 = wp[3*HID];
            wp += 4*HID;
            #pragma unroll
            for (int b = 0; b < 4; ++b) {
                float4 a = *(const float4*)(xb + (size_t)b*2*HID*4 + (size_t)k4*16);
                acc[b] = fmaf(a.x,w0,acc[b]); acc[b] = fmaf(a.y,w1,acc[b]);
                acc[b] = fmaf(a.z,w2,acc[b]); acc[b] = fmaf(a.w,w3,acc[b]);
            }
        }
    }
    // LayerNorm over cols per node
    {
        float s[4], q[4];
        #pragma unroll
        for (int b = 0; b < 4; ++b) { s[b] = acc[b]; q[b] = acc[b]*acc[b]; }
        #pragma unroll
        for (int msk = 1; msk < 64; msk <<= 1) {
            #pragma unroll
            for (int b = 0; b < 4; ++b) { s[b] += __shfl_xor(s[b], msk); q[b] += __shfl_xor(q[b], msk); }
        }
        const int wv = tid >> 6;
        if ((tid & 63) == 0) {
            #pragma unroll
            for (int b = 0; b < 4; ++b) { sS[wv][b] = s[b]; sQ[wv][b] = q[b]; }
        }
        __syncthreads();
        const float G = g2[o], B = bt2[o];
        #pragma unroll
        for (int b = 0; b < 4; ++b) {
            float st = sS[half*2][b] + sS[half*2+1][b];
            float qt = sQ[half*2][b] + sQ[half*2+1][b];
            float mu  = st * (1.0f/HID);
            float var = qt * (1.0f/HID) - mu*mu;
            float inv = rsqrtf(var + 1e-5f);
            sY[half*4+b][o] = siluf(fmaf((acc[b]-mu)*inv, G, B));
        }
    }
    __syncthreads();

    float acc2[4];
    {
        const float b2 = bn2[o];
        #pragma unroll
        for (int b = 0; b < 4; ++b) acc2[b] = b2;
        const float* wp = Wn2 + o;
        const char*  yb = (const char*)&sY[half*4][0];
        for (int k4 = 0; k4 < HID/4; ++k4) {
            float w0 = wp[0*HID], w1 = wp[1*HID], w2 = wp[2*HID], w3 = wp[3*HID];
            wp += 4*HID;
            #pragma unroll
            for (int b = 0; b < 4; ++b) {
                float4 a = *(const float4*)(yb + (size_t)b*HID*4 + (size_t)k4*16);
                acc2[b] = fmaf(a.x,w0,acc2[b]); acc2[b] = fmaf(a.y,w1,acc2[b]);
                acc2[b] = fmaf(a.z,w2,acc2[b]); acc2[b] = fmaf(a.w,w3,acc2[b]);
            }
        }
    }
    #pragma unroll
    for (int b = 0; b < 4; ++b)
        hh[(size_t)(node0+half*4+b)*HID + o] = sX[half*4+b][o] + acc2[b];
}

// ---------------------------------------------------------------- output head
__global__ __launch_bounds__(HID) void out_k(
    const float* __restrict__ hh, const float* __restrict__ Woe,
    const float* __restrict__ boe, const float* __restrict__ Wf,
    const float* __restrict__ bf, float* __restrict__ out)
{
    __shared__ float sH[HID];
    const int lig = blockIdx.x, tid = threadIdx.x;
    float s = 0.0f;
    const float* base = hh + (size_t)lig*KAT*HID + tid;
    #pragma unroll 8
    for (int a = 0; a < KAT; ++a) s += base[a*HID];
    sH[tid] = s * (1.0f/KAT);
    __syncthreads();

    float contrib = 0.0f;
    if (tid < OUTF) {
        float p = boe[tid];
        #pragma unroll 4
        for (int i = 0; i < HID; ++i)
            p = fmaf(sH[i], Woe[i*OUTF + tid], p);
        contrib = p * Wf[tid];
    }
    #pragma unroll
    for (int m = 1; m < 64; m <<= 1) contrib += __shfl_xor(contrib, m);
    if (tid == 0) out[lig] = contrib + bf[0];
}

// ---------------------------------------------------------------- launch
extern "C" void kernel_launch(void* const* d_in, const int* in_sizes, int n_in,
                              void* d_out, int out_size, void* d_ws, size_t ws_size,
                              hipStream_t stream)
{
    (void)in_sizes; (void)n_in; (void)out_size; (void)ws_size;
    const float* x    = (const float*)d_in[0];
    const float* h    = (const float*)d_in[1];
    const int*   t    = (const int*)d_in[2];
    const int*   edges= (const int*)d_in[3];
    const int*   tb   = (const int*)d_in[4];
    const float* temb = (const float*)d_in[8];
    const float* Win  = (const float*)d_in[9];
    const float* bin  = (const float*)d_in[10];
    const float* We1  = (const float*)d_in[11];
    const float* be1  = (const float*)d_in[12];
    const float* g1   = (const float*)d_in[13];
    const float* bt1  = (const float*)d_in[14];
    const float* We2  = (const float*)d_in[15];
    const float* be2  = (const float*)d_in[16];
    const float* Watt = (const float*)d_in[17];
    const float* batt = (const float*)d_in[18];
    const float* Wn1  = (const float*)d_in[19];
    const float* bn1  = (const float*)d_in[20];
    const float* g2   = (const float*)d_in[21];
    const float* bt2  = (const float*)d_in[22];
    const float* Wn2  = (const float*)d_in[23];
    const float* bn2  = (const float*)d_in[24];
    const float* Woe  = (const float*)d_in[25];
    const float* boe  = (const float*)d_in[26];
    const float* Wf   = (const float*)d_in[27];
    const float* bf   = (const float*)d_in[28];
    float* out = (float*)d_out;

    float* hh  = (float*)d_ws;                       // [N,128] 16 MB
    float* agg = hh + (size_t)NNODES*HID;            // [N,128] 16 MB

    embed_k<<<NNODES, HID, 0, stream>>>(h, t, temb, Win, bin, hh);
    for (int l = 0; l < 4; ++l) {
        edge_k<<<NNODES/NPB, 256, 0, stream>>>(hh, x, edges + NEDGES, tb, temb,
            We1 + (size_t)l*(2*HID+36)*HID, be1 + l*HID, g1 + l*HID, bt1 + l*HID,
            We2 + (size_t)l*HID*HID, be2 + l*HID,
            Watt + l*HID, batt + l, agg);
        node_k<<<NNODES/NPBN, 256, 0, stream>>>(hh, agg,
            Wn1 + (size_t)l*2*HID*HID, bn1 + l*HID, g2 + l*HID, bt2 + l*HID,
            Wn2 + (size_t)l*HID*HID, bn2 + l*HID);
    }
    out_k<<<NLIG, HID, 0, stream>>>(hh, Woe, boe, Wf, bf, out);
}

// Round 3
// 1497.215 us; speedup vs baseline: 2.5176x; 1.4600x over previous
//
#include <hip/hip_runtime.h>
#include <math.h>

#define NNODES 32768
#define NLIG   1024
#define KAT    32
#define KNN    8
#define NEDGES (NNODES*KNN)
#define HID    128
#define TF     16
#define NG     20
#define OUTF   64

#define NPB    4            // nodes per edge-block
#define EPB    32           // edges per edge-block
#define K1     320          // padded GEMM1 K (292 -> 320)
#define MIDSTR 132          // sMid row stride (floats)
#define NPBN   8            // nodes per node-block

typedef unsigned short u16;
typedef __attribute__((__ext_vector_type__(8))) short bfx8;
typedef __attribute__((__ext_vector_type__(4))) float f32x4;

union U8 { u16 a[8]; bfx8 v; };

__device__ __forceinline__ float siluf(float v) {
    return __fdividef(v, 1.0f + __expf(-v));
}
__device__ __forceinline__ float sigf(float v) {
    return __fdividef(1.0f, 1.0f + __expf(-v));
}
__device__ __forceinline__ u16 bf16_rn(float f) {
    union { float f; unsigned u; } v; v.f = f;
    unsigned r = v.u + 0x7FFFu + ((v.u >> 16) & 1u);
    return (u16)(r >> 16);
}
__device__ __forceinline__ float bf16_tof(u16 u) {
    union { unsigned u; float f; } v; v.u = ((unsigned)u) << 16;
    return v.f;
}
__device__ __forceinline__ f32x4 mfma3(bfx8 ah, bfx8 al, bfx8 wh, bfx8 wl, f32x4 c) {
    c = __builtin_amdgcn_mfma_f32_16x16x32_bf16(ah, wh, c, 0, 0, 0);
    c = __builtin_amdgcn_mfma_f32_16x16x32_bf16(ah, wl, c, 0, 0, 0);
    c = __builtin_amdgcn_mfma_f32_16x16x32_bf16(al, wh, c, 0, 0, 0);
    return c;
}

// ---------------------------------------------------------------- prep:
// split weights to bf16 hi/lo, transposed [col][K]; temb hi/lo.
#define PREP_TEMB 16000
#define PREP_W1   (4*128*K1)      // 163840
#define PREP_W2   (4*128*128)     // 65536
#define PREP_TOT  (PREP_TEMB + PREP_W1 + PREP_W2)

__global__ __launch_bounds__(256) void prep_k(
    const float* __restrict__ temb, const float* __restrict__ We1,
    const float* __restrict__ We2,
    u16* __restrict__ tembH, u16* __restrict__ tembL,
    u16* __restrict__ W1TH, u16* __restrict__ W1TL,
    u16* __restrict__ W2TH, u16* __restrict__ W2TL)
{
    int i = blockIdx.x*256 + threadIdx.x;
    if (i >= PREP_TOT) return;
    float v; u16 *dh, *dl; int di;
    if (i < PREP_TEMB) {
        v = temb[i]; dh = tembH; dl = tembL; di = i;
    } else if (i < PREP_TEMB + PREP_W1) {
        int j = i - PREP_TEMB; di = j; dh = W1TH; dl = W1TL;
        int l = j / (128*K1); int r = j - l*(128*K1);
        int col = r / K1, k = r - col*K1;
        v = (k < 292) ? We1[(size_t)l*292*128 + (size_t)k*128 + col] : 0.0f;
    } else {
        int j = i - PREP_TEMB - PREP_W1; di = j; dh = W2TH; dl = W2TL;
        int l = j / (128*128); int r = j - l*(128*128);
        int col = r >> 7, k = r & 127;
        v = We2[(size_t)l*128*128 + (size_t)k*128 + col];
    }
    u16 h = bf16_rn(v);
    dh[di] = h;
    dl[di] = bf16_rn(v - bf16_tof(h));
}

// ---------------------------------------------------------------- embed
__global__ __launch_bounds__(HID) void embed_k(
    const float* __restrict__ h, const int* __restrict__ t,
    const float* __restrict__ temb, const float* __restrict__ Win,
    const float* __restrict__ bin, float* __restrict__ hh,
    u16* __restrict__ hhH, u16* __restrict__ hhL)
{
    __shared__ float sIn[2*TF];
    const int node = blockIdx.x, tid = threadIdx.x;
    if (tid < TF)        sIn[tid] = h[node*TF + tid];
    else if (tid < 2*TF) sIn[tid] = temb[t[node]*TF + (tid-TF)];
    __syncthreads();
    float acc = bin[tid];
    #pragma unroll
    for (int i = 0; i < 2*TF; ++i)
        acc = fmaf(sIn[i], Win[i*HID + tid], acc);
    const int idx = node*HID + tid;
    hh[idx] = acc;
    u16 hb = bf16_rn(acc);
    hhH[idx] = hb;
    hhL[idx] = bf16_rn(acc - bf16_tof(hb));
}

// ---------------------------------------------------------------- edge (MFMA)
__global__ __launch_bounds__(256) void edge_k(
    const u16* __restrict__ hhH, const u16* __restrict__ hhL,
    const float* __restrict__ x,
    const int* __restrict__ ecol, const int* __restrict__ tbond,
    const u16* __restrict__ tembH, const u16* __restrict__ tembL,
    const u16* __restrict__ W1TH, const u16* __restrict__ W1TL,
    const u16* __restrict__ W2TH, const u16* __restrict__ W2TL,
    const float* __restrict__ be1, const float* __restrict__ g1,
    const float* __restrict__ bt1, const float* __restrict__ be2,
    const float* __restrict__ Watt, const float* __restrict__ batt,
    float* __restrict__ agg)
{
    // sBuf serves two lives: (1) tail chunks (temb/smear) for GEMM1 steps 8-9,
    // (2) post-LN activations (GEMM2 A). Both XOR-swizzled at 16B granularity.
    __shared__ u16 sBufH[EPB*128];
    __shared__ u16 sBufL[EPB*128];
    __shared__ float sMid[EPB*MIDSTR];
    __shared__ float sAP[4][EPB];
    __shared__ float sAttv[EPB];

    const int tid  = threadIdx.x;
    const int node0 = blockIdx.x * NPB;
    const int w = tid >> 6, lane = tid & 63, lr = lane & 15, lh = lane >> 4;

    // ---- phase A: build tail chunks [32 rows][chunks 0..7 = temb(2)|smear(3)|zero(3)]
    {
        const int row = tid & 31, part = tid >> 5;
        const int rno = node0 + (row >> 3);
        U8 vh, vl;
        if (part < 2) {
            const int c = ecol[node0*KNN + row];
            int sbi = rno*(KAT-1) + c - (rno/KAT)*KAT - (rno < c ? 1 : 0);
            const int tb = tbond[sbi];
            const u16* th = tembH + tb*TF + part*8;
            const u16* tl = tembL + tb*TF + part*8;
            #pragma unroll
            for (int j = 0; j < 8; ++j) { vh.a[j] = th[j]; vl.a[j] = tl[j]; }
        } else if (part < 5) {
            const int c = ecol[node0*KNN + row];
            float dx = x[3*rno+0]-x[3*c+0];
            float dy = x[3*rno+1]-x[3*c+1];
            float dz = x[3*rno+2]-x[3*c+2];
            float dist = fminf(sqrtf(dx*dx+dy*dy+dz*dz), 4.0f);
            const float Cc = 0.12220674183617694f;   // log2(5)/19
            #pragma unroll
            for (int j = 0; j < 8; ++j) {
                int g = (part-2)*8 + j;
                float v = 0.0f;
                if (g < NG) {
                    float og = exp2f(Cc*(float)g) - 1.0f;
                    int gm = (g > 0) ? g : 1;
                    float d = exp2f(Cc*(float)gm) - exp2f(Cc*(float)(gm-1));
                    float dd = dist - og;
                    v = __expf(-0.5f/(d*d)*dd*dd);
                }
                u16 hb = bf16_rn(v);
                vh.a[j] = hb; vl.a[j] = bf16_rn(v - bf16_tof(hb));
            }
        } else {
            #pragma unroll
            for (int j = 0; j < 8; ++j) { vh.a[j] = 0; vl.a[j] = 0; }
        }
        const int idx = row*128 + ((part*8) ^ ((row & 7) << 3));
        *(bfx8*)&sBufH[idx] = vh.v;
        *(bfx8*)&sBufL[idx] = vl.v;
    }

    // ---- per-lane GEMM1 pointer setup (rows row0 = lr, row1 = 16+lr) ----
    const int row0 = lr, row1 = 16 + lr;
    const int rn0 = node0 + (row0 >> 3), rn1 = node0 + (row1 >> 3);
    const int cn0 = ecol[node0*KNN + row0], cn1 = ecol[node0*KNN + row1];
    const u16* aRH0 = hhH + (size_t)rn0*HID + lh*8;
    const u16* aRH1 = hhH + (size_t)rn1*HID + lh*8;
    const u16* aRL0 = hhL + (size_t)rn0*HID + lh*8;
    const u16* aRL1 = hhL + (size_t)rn1*HID + lh*8;
    const u16* aCH0 = hhH + (size_t)cn0*HID + lh*8;
    const u16* aCH1 = hhH + (size_t)cn1*HID + lh*8;
    const u16* aCL0 = hhL + (size_t)cn0*HID + lh*8;
    const u16* aCL1 = hhL + (size_t)cn1*HID + lh*8;
    const int colB0 = w*32 + lr, colB1 = colB0 + 16;
    const u16* bH0 = W1TH + (size_t)colB0*K1 + lh*8;
    const u16* bH1 = W1TH + (size_t)colB1*K1 + lh*8;
    const u16* bL0 = W1TL + (size_t)colB0*K1 + lh*8;
    const u16* bL1 = W1TL + (size_t)colB1*K1 + lh*8;

    __syncthreads();   // sBuf tail ready

    // ---- GEMM1: [32 x 320] @ [320 x 128], split-bf16 (3 products) ------
    f32x4 acc00 = {0,0,0,0}, acc01 = {0,0,0,0}, acc10 = {0,0,0,0}, acc11 = {0,0,0,0};

#define G1STEP(PAH0,PAH1,PAL0,PAL1,BOFS) {                                   \
    bfx8 ah0 = *(const bfx8*)(PAH0), ah1 = *(const bfx8*)(PAH1);             \
    bfx8 al0 = *(const bfx8*)(PAL0), al1 = *(const bfx8*)(PAL1);             \
    bfx8 wh0 = *(const bfx8*)(bH0+(BOFS)), wh1 = *(const bfx8*)(bH1+(BOFS)); \
    bfx8 wl0 = *(const bfx8*)(bL0+(BOFS)), wl1 = *(const bfx8*)(bL1+(BOFS)); \
    acc00 = mfma3(ah0, al0, wh0, wl0, acc00);                                \
    acc01 = mfma3(ah0, al0, wh1, wl1, acc01);                                \
    acc10 = mfma3(ah1, al1, wh0, wl0, acc10);                                \
    acc11 = mfma3(ah1, al1, wh1, wl1, acc11); }

    #pragma unroll
    for (int s = 0; s < 4; ++s)      // k 0..127: hh[rownode]
        G1STEP(aRH0+32*s, aRH1+32*s, aRL0+32*s, aRL1+32*s, 32*s);
    #pragma unroll
    for (int s = 4; s < 8; ++s)      // k 128..255: hh[colnode]
        G1STEP(aCH0+32*(s-4), aCH1+32*(s-4), aCL0+32*(s-4), aCL1+32*(s-4), 32*s);
    #pragma unroll
    for (int s = 8; s < 10; ++s) {   // k 256..319: temb|smear|pad from LDS
        const int co = (4*(s-8) + lh) * 8;
        const int i0 = row0*128 + (co ^ ((row0 & 7) << 3));
        const int i1 = row1*128 + (co ^ ((row1 & 7) << 3));
        G1STEP(&sBufH[i0], &sBufH[i1], &sBufL[i0], &sBufL[i1], 32*s);
    }

    // ---- C1 (+bias) -> sMid --------------------------------------------
    {
        const float b10 = be1[colB0], b11 = be1[colB1];
        #pragma unroll
        for (int j = 0; j < 4; ++j) {
            const int r0 = 4*lh + j;
            sMid[r0*MIDSTR + colB0]        = acc00[j] + b10;
            sMid[r0*MIDSTR + colB1]        = acc01[j] + b11;
            sMid[(16+r0)*MIDSTR + colB0]   = acc10[j] + b10;
            sMid[(16+r0)*MIDSTR + colB1]   = acc11[j] + b11;
        }
    }
    __syncthreads();   // also guards sBuf reuse below

    // ---- LayerNorm + SiLU, split-write to sBuf (GEMM2 A) ---------------
    {
        const int e = tid >> 3, c0 = (tid & 7) * 16;
        const float* mrow = &sMid[e*MIDSTR];
        float4 v0 = *(const float4*)&mrow[c0+0];
        float4 v1 = *(const float4*)&mrow[c0+4];
        float4 v2 = *(const float4*)&mrow[c0+8];
        float4 v3 = *(const float4*)&mrow[c0+12];
        float s = v0.x+v0.y+v0.z+v0.w + v1.x+v1.y+v1.z+v1.w
                + v2.x+v2.y+v2.z+v2.w + v3.x+v3.y+v3.z+v3.w;
        float q = v0.x*v0.x+v0.y*v0.y+v0.z*v0.z+v0.w*v0.w
                + v1.x*v1.x+v1.y*v1.y+v1.z*v1.z+v1.w*v1.w
                + v2.x*v2.x+v2.y*v2.y+v2.z*v2.z+v2.w*v2.w
                + v3.x*v3.x+v3.y*v3.y+v3.z*v3.z+v3.w*v3.w;
        #pragma unroll
        for (int m = 4; m >= 1; m >>= 1) { s += __shfl_xor(s, m); q += __shfl_xor(q, m); }
        float mu  = s * (1.0f/HID);
        float var = q * (1.0f/HID) - mu*mu;
        float inv = rsqrtf(var + 1e-5f);
        float y[16];
        {
            const float4 G0 = *(const float4*)&g1[c0+0],  G1v = *(const float4*)&g1[c0+4];
            const float4 G2 = *(const float4*)&g1[c0+8],  G3 = *(const float4*)&g1[c0+12];
            const float4 B0 = *(const float4*)&bt1[c0+0], B1 = *(const float4*)&bt1[c0+4];
            const float4 B2 = *(const float4*)&bt1[c0+8], B3 = *(const float4*)&bt1[c0+12];
            y[0]=siluf(fmaf((v0.x-mu)*inv,G0.x,B0.x)); y[1]=siluf(fmaf((v0.y-mu)*inv,G0.y,B0.y));
            y[2]=siluf(fmaf((v0.z-mu)*inv,G0.z,B0.z)); y[3]=siluf(fmaf((v0.w-mu)*inv,G0.w,B0.w));
            y[4]=siluf(fmaf((v1.x-mu)*inv,G1v.x,B1.x)); y[5]=siluf(fmaf((v1.y-mu)*inv,G1v.y,B1.y));
            y[6]=siluf(fmaf((v1.z-mu)*inv,G1v.z,B1.z)); y[7]=siluf(fmaf((v1.w-mu)*inv,G1v.w,B1.w));
            y[8]=siluf(fmaf((v2.x-mu)*inv,G2.x,B2.x)); y[9]=siluf(fmaf((v2.y-mu)*inv,G2.y,B2.y));
            y[10]=siluf(fmaf((v2.z-mu)*inv,G2.z,B2.z)); y[11]=siluf(fmaf((v2.w-mu)*inv,G2.w,B2.w));
            y[12]=siluf(fmaf((v3.x-mu)*inv,G3.x,B3.x)); y[13]=siluf(fmaf((v3.y-mu)*inv,G3.y,B3.y));
            y[14]=siluf(fmaf((v3.z-mu)*inv,G3.z,B3.z)); y[15]=siluf(fmaf((v3.w-mu)*inv,G3.w,B3.w));
        }
        U8 ha, hb, la, lb;
        #pragma unroll
        for (int j = 0; j < 8; ++j) {
            u16 h0 = bf16_rn(y[j]);   ha.a[j] = h0; la.a[j] = bf16_rn(y[j]   - bf16_tof(h0));
            u16 h1 = bf16_rn(y[8+j]); hb.a[j] = h1; lb.a[j] = bf16_rn(y[8+j] - bf16_tof(h1));
        }
        const int swz = (e & 7) << 3;
        const int ia = e*128 + (c0 ^ swz);
        const int ib = e*128 + ((c0+8) ^ swz);
        *(bfx8*)&sBufH[ia] = ha.v; *(bfx8*)&sBufH[ib] = hb.v;
        *(bfx8*)&sBufL[ia] = la.v; *(bfx8*)&sBufL[ib] = lb.v;
    }
    __syncthreads();

    // ---- GEMM2: [32 x 128] @ [128 x 128] -------------------------------
    f32x4 d00 = {0,0,0,0}, d01 = {0,0,0,0}, d10 = {0,0,0,0}, d11 = {0,0,0,0};
    {
        const u16* b2H0 = W2TH + (size_t)colB0*HID + lh*8;
        const u16* b2H1 = W2TH + (size_t)colB1*HID + lh*8;
        const u16* b2L0 = W2TL + (size_t)colB0*HID + lh*8;
        const u16* b2L1 = W2TL + (size_t)colB1*HID + lh*8;
        const int swz0 = (row0 & 7) << 3, swz1 = (row1 & 7) << 3;
        #pragma unroll
        for (int s = 0; s < 4; ++s) {
            const int ko = s*32 + lh*8;
            const int i0 = row0*128 + (ko ^ swz0);
            const int i1 = row1*128 + (ko ^ swz1);
            bfx8 ah0 = *(const bfx8*)&sBufH[i0], ah1 = *(const bfx8*)&sBufH[i1];
            bfx8 al0 = *(const bfx8*)&sBufL[i0], al1 = *(const bfx8*)&sBufL[i1];
            bfx8 wh0 = *(const bfx8*)(b2H0 + 32*s), wh1 = *(const bfx8*)(b2H1 + 32*s);
            bfx8 wl0 = *(const bfx8*)(b2L0 + 32*s), wl1 = *(const bfx8*)(b2L1 + 32*s);
            d00 = mfma3(ah0, al0, wh0, wl0, d00);
            d01 = mfma3(ah0, al0, wh1, wl1, d01);
            d10 = mfma3(ah1, al1, wh0, wl0, d10);
            d11 = mfma3(ah1, al1, wh1, wl1, d11);
        }
    }

    // ---- SiLU + attention gate -----------------------------------------
    float m00[4], m01[4], m10[4], m11[4];
    {
        const float b20 = be2[colB0], b21 = be2[colB1];
        #pragma unroll
        for (int j = 0; j < 4; ++j) {
            m00[j] = siluf(d00[j] + b20); m01[j] = siluf(d01[j] + b21);
            m10[j] = siluf(d10[j] + b20); m11[j] = siluf(d11[j] + b21);
        }
    }
    {
        const float wa0 = Watt[colB0], wa1 = Watt[colB1];
        float p0[4], p1[4];
        #pragma unroll
        for (int j = 0; j < 4; ++j) {
            p0[j] = m00[j]*wa0 + m01[j]*wa1;
            p1[j] = m10[j]*wa0 + m11[j]*wa1;
        }
        #pragma unroll
        for (int msk = 1; msk < 16; msk <<= 1) {
            #pragma unroll
            for (int j = 0; j < 4; ++j) {
                p0[j] += __shfl_xor(p0[j], msk);
                p1[j] += __shfl_xor(p1[j], msk);
            }
        }
        if (lr == 0) {
            #pragma unroll
            for (int j = 0; j < 4; ++j) {
                sAP[w][4*lh + j]      = p0[j];
                sAP[w][16 + 4*lh + j] = p1[j];
            }
        }
    }
    __syncthreads();
    if (tid < EPB)
        sAttv[tid] = sigf(sAP[0][tid] + sAP[1][tid] + sAP[2][tid] + sAP[3][tid] + batt[0]);
    __syncthreads();

    // ---- gated aggregate -> agg ----------------------------------------
    {
        float s00 = 0.f, s01 = 0.f, s10 = 0.f, s11 = 0.f;
        #pragma unroll
        for (int j = 0; j < 4; ++j) {
            const float a0 = sAttv[4*lh + j];
            const float a1 = sAttv[16 + 4*lh + j];
            s00 += m00[j]*a0; s01 += m01[j]*a0;
            s10 += m10[j]*a1; s11 += m11[j]*a1;
        }
        s00 += __shfl_xor(s00, 16); s01 += __shfl_xor(s01, 16);
        s10 += __shfl_xor(s10, 16); s11 += __shfl_xor(s11, 16);
        if (lh == 0) {
            agg[(size_t)(node0+0)*HID + colB0] = s00*0.2f;
            agg[(size_t)(node0+0)*HID + colB1] = s01*0.2f;
            agg[(size_t)(node0+2)*HID + colB0] = s10*0.2f;
            agg[(size_t)(node0+2)*HID + colB1] = s11*0.2f;
        } else if (lh == 2) {
            agg[(size_t)(node0+1)*HID + colB0] = s00*0.2f;
            agg[(size_t)(node0+1)*HID + colB1] = s01*0.2f;
            agg[(size_t)(node0+3)*HID + colB0] = s10*0.2f;
            agg[(size_t)(node0+3)*HID + colB1] = s11*0.2f;
        }
    }
#undef G1STEP
}

// ---------------------------------------------------------------- node model
__global__ __launch_bounds__(256) void node_k(
    float* __restrict__ hh, const float* __restrict__ agg,
    const float* __restrict__ Wn1, const float* __restrict__ bn1,
    const float* __restrict__ g2, const float* __restrict__ bt2,
    const float* __restrict__ Wn2, const float* __restrict__ bn2,
    u16* __restrict__ hhH, u16* __restrict__ hhL)
{
    __shared__ float sX[NPBN][2*HID];
    __shared__ float sY[NPBN][HID];
    __shared__ float sS[4][4], sQ[4][4];

    const int tid   = threadIdx.x;
    const int node0 = blockIdx.x * NPBN;
    const int o     = tid & (HID-1);
    const int half  = tid >> 7;

    for (int idx = tid; idx < NPBN*64; idx += 256) {
        int n = idx >> 6, k4 = idx & 63;
        float4 v;
        if (k4 < 32) v = *(const float4*)&hh [(size_t)(node0+n)*HID + k4*4];
        else         v = *(const float4*)&agg[(size_t)(node0+n)*HID + (k4-32)*4];
        *(float4*)&sX[n][k4*4] = v;
    }
    __syncthreads();

    float acc[4];
    {
        const float b1 = bn1[o];
        #pragma unroll
        for (int b = 0; b < 4; ++b) acc[b] = b1;
        const float* wp = Wn1 + o;
        const char*  xb = (const char*)&sX[half*4][0];
        for (int k4 = 0; k4 < (2*HID)/4; ++k4) {
            float w0 = wp[0*HID], w1 = wp[1*HID], w2 = wp[2*HID], w3 = wp[3*HID];
            wp += 4*HID;
            #pragma unroll
            for (int b = 0; b < 4; ++b) {
                float4 a = *(const float4*)(xb + (size_t)b*2*HID*4 + (size_t)k4*16);
                acc[b] = fmaf(a.x,w0,acc[b]); acc[b] = fmaf(a.y,w1,acc[b]);
                acc[b] = fmaf(a.z,w2,acc[b]); acc[b] = fmaf(a.w,w3,acc[b]);
            }
        }
    }
    {
        float s[4], q[4];
        #pragma unroll
        for (int b = 0; b < 4; ++b) { s[b] = acc[b]; q[b] = acc[b]*acc[b]; }
        #pragma unroll
        for (int msk = 1; msk < 64; msk <<= 1) {
            #pragma unroll
            for (int b = 0; b < 4; ++b) { s[b] += __shfl_xor(s[b], msk); q[b] += __shfl_xor(q[b], msk); }
        }
        const int wv = tid >> 6;
        if ((tid & 63) == 0) {
            #pragma unroll
            for (int b = 0; b < 4; ++b) { sS[wv][b] = s[b]; sQ[wv][b] = q[b]; }
        }
        __syncthreads();
        const float G = g2[o], B = bt2[o];
        #pragma unroll
        for (int b = 0; b < 4; ++b) {
            float st = sS[half*2][b] + sS[half*2+1][b];
            float qt = sQ[half*2][b] + sQ[half*2+1][b];
            float mu  = st * (1.0f/HID);
            float var = qt * (1.0f/HID) - mu*mu;
            float inv = rsqrtf(var + 1e-5f);
            sY[half*4+b][o] = siluf(fmaf((acc[b]-mu)*inv, G, B));
        }
    }
    __syncthreads();

    float acc2[4];
    {
        const float b2 = bn2[o];
        #pragma unroll
        for (int b = 0; b < 4; ++b) acc2[b] = b2;
        const float* wp = Wn2 + o;
        const char*  yb = (const char*)&sY[half*4][0];
        for (int k4 = 0; k4 < HID/4; ++k4) {
            float w0 = wp[0*HID], w1 = wp[1*HID], w2 = wp[2*HID], w3 = wp[3*HID];
            wp += 4*HID;
            #pragma unroll
            for (int b = 0; b < 4; ++b) {
                float4 a = *(const float4*)(yb + (size_t)b*HID*4 + (size_t)k4*16);
                acc2[b] = fmaf(a.x,w0,acc2[b]); acc2[b] = fmaf(a.y,w1,acc2[b]);
                acc2[b] = fmaf(a.z,w2,acc2[b]); acc2[b] = fmaf(a.w,w3,acc2[b]);
            }
        }
    }
    #pragma unroll
    for (int b = 0; b < 4; ++b) {
        const size_t idx = (size_t)(node0+half*4+b)*HID + o;
        const float hv = sX[half*4+b][o] + acc2[b];
        hh[idx] = hv;
        u16 hb = bf16_rn(hv);
        hhH[idx] = hb;
        hhL[idx] = bf16_rn(hv - bf16_tof(hb));
    }
}

// ---------------------------------------------------------------- output head
__global__ __launch_bounds__(HID) void out_k(
    const float* __restrict__ hh, const float* __restrict__ Woe,
    const float* __restrict__ boe, const float* __restrict__ Wf,
    const float* __restrict__ bf, float* __restrict__ out)
{
    __shared__ float sH[HID];
    const int lig = blockIdx.x, tid = threadIdx.x;
    float s = 0.0f;
    const float* base = hh + (size_t)lig*KAT*HID + tid;
    #pragma unroll 8
    for (int a = 0; a < KAT; ++a) s += base[a*HID];
    sH[tid] = s * (1.0f/KAT);
    __syncthreads();

    float contrib = 0.0f;
    if (tid < OUTF) {
        float p = boe[tid];
        #pragma unroll 4
        for (int i = 0; i < HID; ++i)
            p = fmaf(sH[i], Woe[i*OUTF + tid], p);
        contrib = p * Wf[tid];
    }
    #pragma unroll
    for (int m = 1; m < 64; m <<= 1) contrib += __shfl_xor(contrib, m);
    if (tid == 0) out[lig] = contrib + bf[0];
}

// ---------------------------------------------------------------- launch
extern "C" void kernel_launch(void* const* d_in, const int* in_sizes, int n_in,
                              void* d_out, int out_size, void* d_ws, size_t ws_size,
                              hipStream_t stream)
{
    (void)in_sizes; (void)n_in; (void)out_size; (void)ws_size;
    const float* x    = (const float*)d_in[0];
    const float* h    = (const float*)d_in[1];
    const int*   t    = (const int*)d_in[2];
    const int*   edges= (const int*)d_in[3];
    const int*   tb   = (const int*)d_in[4];
    const float* temb = (const float*)d_in[8];
    const float* Win  = (const float*)d_in[9];
    const float* bin  = (const float*)d_in[10];
    const float* We1  = (const float*)d_in[11];
    const float* be1  = (const float*)d_in[12];
    const float* g1   = (const float*)d_in[13];
    const float* bt1  = (const float*)d_in[14];
    const float* We2  = (const float*)d_in[15];
    const float* be2  = (const float*)d_in[16];
    const float* Watt = (const float*)d_in[17];
    const float* batt = (const float*)d_in[18];
    const float* Wn1  = (const float*)d_in[19];
    const float* bn1  = (const float*)d_in[20];
    const float* g2   = (const float*)d_in[21];
    const float* bt2  = (const float*)d_in[22];
    const float* Wn2  = (const float*)d_in[23];
    const float* bn2  = (const float*)d_in[24];
    const float* Woe  = (const float*)d_in[25];
    const float* boe  = (const float*)d_in[26];
    const float* Wf   = (const float*)d_in[27];
    const float* bf   = (const float*)d_in[28];
    float* out = (float*)d_out;

    char* wsb = (char*)d_ws;
    float* hh   = (float*)(wsb);                       // 16 MB
    float* agg  = (float*)(wsb + ((size_t)16<<20));    // 16 MB
    u16* hhH    = (u16*)(wsb + ((size_t)32<<20));      // 8 MB
    u16* hhL    = (u16*)(wsb + ((size_t)40<<20));      // 8 MB
    u16* tembH  = (u16*)(wsb + ((size_t)48<<20));
    u16* tembL  = tembH + PREP_TEMB;
    u16* W1TH   = tembL + PREP_TEMB;
    u16* W1TL   = W1TH + PREP_W1;
    u16* W2TH   = W1TL + PREP_W1;
    u16* W2TL   = W2TH + PREP_W2;

    prep_k<<<(PREP_TOT + 255)/256, 256, 0, stream>>>(
        temb, We1, We2, tembH, tembL, W1TH, W1TL, W2TH, W2TL);

    embed_k<<<NNODES, HID, 0, stream>>>(h, t, temb, Win, bin, hh, hhH, hhL);

    for (int l = 0; l < 4; ++l) {
        edge_k<<<NNODES/NPB, 256, 0, stream>>>(
            hhH, hhL, x, edges + NEDGES, tb, tembH, tembL,
            W1TH + (size_t)l*128*K1, W1TL + (size_t)l*128*K1,
            W2TH + (size_t)l*128*128, W2TL + (size_t)l*128*128,
            be1 + l*HID, g1 + l*HID, bt1 + l*HID, be2 + l*HID,
            Watt + l*HID, batt + l, agg);
        node_k<<<NNODES/NPBN, 256, 0, stream>>>(hh, agg,
            Wn1 + (size_t)l*2*HID*HID, bn1 + l*HID, g2 + l*HID, bt2 + l*HID,
            Wn2 + (size_t)l*HID*HID, bn2 + l*HID, hhH, hhL);
    }
    out_k<<<NLIG, HID, 0, stream>>>(hh, Woe, boe, Wf, bf, out);
}

// Round 5
// 1125.526 us; speedup vs baseline: 3.3490x; 1.3302x over previous
//
#include <hip/hip_runtime.h>
#include <math.h>

#define NNODES 32768
#define NLIG   1024
#define KAT    32
#define KNN    8
#define NEDGES (NNODES*KNN)
#define HID    128
#define TF     16
#define NG     20
#define OUTF   64

#define NPB    4            // nodes per edge-block
#define EPB    32           // edges per edge-block
#define K1     320          // padded GEMM1 K (292 -> 320)
#define MIDSTR 132          // sMid row stride (floats)

typedef unsigned short u16;
typedef __attribute__((__ext_vector_type__(8))) short bfx8;
typedef __attribute__((__ext_vector_type__(4))) float f32x4;

union U8 { u16 a[8]; bfx8 v; };

__device__ __forceinline__ float siluf(float v) {
    return __fdividef(v, 1.0f + __expf(-v));
}
__device__ __forceinline__ float sigf(float v) {
    return __fdividef(1.0f, 1.0f + __expf(-v));
}
__device__ __forceinline__ u16 bf16_rn(float f) {
    union { float f; unsigned u; } v; v.f = f;
    unsigned r = v.u + 0x7FFFu + ((v.u >> 16) & 1u);
    return (u16)(r >> 16);
}
__device__ __forceinline__ float bf16_tof(u16 u) {
    union { unsigned u; float f; } v; v.u = ((unsigned)u) << 16;
    return v.f;
}
__device__ __forceinline__ f32x4 mfma3(bfx8 ah, bfx8 al, bfx8 wh, bfx8 wl, f32x4 c) {
    c = __builtin_amdgcn_mfma_f32_16x16x32_bf16(ah, wh, c, 0, 0, 0);
    c = __builtin_amdgcn_mfma_f32_16x16x32_bf16(ah, wl, c, 0, 0, 0);
    c = __builtin_amdgcn_mfma_f32_16x16x32_bf16(al, wh, c, 0, 0, 0);
    return c;
}
__device__ __forceinline__ void wragg(u16* __restrict__ H, u16* __restrict__ L,
                                      size_t i, float v) {
    u16 hb = bf16_rn(v);
    H[i] = hb; L[i] = bf16_rn(v - bf16_tof(hb));
}

// ---------------------------------------------------------------- prep
#define PREP_TEMB 16000
#define PREP_W1   (4*128*K1)       // 163840
#define PREP_W2   (4*128*128)      // 65536
#define PREP_WN1  (4*128*256)      // 131072
#define PREP_WN2  (4*128*128)      // 65536
#define PREP_TOT  (PREP_TEMB+PREP_W1+PREP_W2+PREP_WN1+PREP_WN2)

__global__ __launch_bounds__(256) void prep_k(
    const float* __restrict__ temb, const float* __restrict__ We1,
    const float* __restrict__ We2,  const float* __restrict__ Wn1,
    const float* __restrict__ Wn2,
    u16* __restrict__ tembH, u16* __restrict__ tembL,
    u16* __restrict__ W1TH, u16* __restrict__ W1TL,
    u16* __restrict__ W2TH, u16* __restrict__ W2TL,
    u16* __restrict__ WN1TH, u16* __restrict__ WN1TL,
    u16* __restrict__ WN2TH, u16* __restrict__ WN2TL)
{
    int i = blockIdx.x*256 + threadIdx.x;
    if (i >= PREP_TOT) return;
    float v; u16 *dh, *dl; int di;
    if (i < PREP_TEMB) {
        v = temb[i]; dh = tembH; dl = tembL; di = i;
    } else if (i < PREP_TEMB + PREP_W1) {
        int j = i - PREP_TEMB; di = j; dh = W1TH; dl = W1TL;
        int l = j / (128*K1); int r = j - l*(128*K1);
        int col = r / K1, k = r - col*K1;
        v = (k < 292) ? We1[(size_t)l*292*128 + (size_t)k*128 + col] : 0.0f;
    } else if (i < PREP_TEMB + PREP_W1 + PREP_W2) {
        int j = i - PREP_TEMB - PREP_W1; di = j; dh = W2TH; dl = W2TL;
        int l = j >> 14; int r = j & 16383;
        int col = r >> 7, k = r & 127;
        v = We2[(size_t)l*16384 + (size_t)k*128 + col];
    } else if (i < PREP_TEMB + PREP_W1 + PREP_W2 + PREP_WN1) {
        int j = i - PREP_TEMB - PREP_W1 - PREP_W2; di = j; dh = WN1TH; dl = WN1TL;
        int l = j >> 15; int r = j & 32767;
        int col = r >> 8, k = r & 255;
        v = Wn1[(size_t)l*32768 + (size_t)k*128 + col];
    } else {
        int j = i - PREP_TEMB - PREP_W1 - PREP_W2 - PREP_WN1; di = j; dh = WN2TH; dl = WN2TL;
        int l = j >> 14; int r = j & 16383;
        int col = r >> 7, k = r & 127;
        v = Wn2[(size_t)l*16384 + (size_t)k*128 + col];
    }
    u16 hb = bf16_rn(v);
    dh[di] = hb;
    dl[di] = bf16_rn(v - bf16_tof(hb));
}

// ---------------------------------------------------------------- embed (8 nodes/block)
__global__ __launch_bounds__(256) void embed_k(
    const float* __restrict__ h, const int* __restrict__ t,
    const float* __restrict__ temb, const float* __restrict__ Win,
    const float* __restrict__ bin, float* __restrict__ hh,
    u16* __restrict__ hhH, u16* __restrict__ hhL)
{
    __shared__ float sIn[8][32];
    const int tid = threadIdx.x;
    {
        const int n = tid >> 5, i = tid & 31;
        const int node = blockIdx.x*8 + n;
        sIn[n][i] = (i < TF) ? h[node*TF + i] : temb[t[node]*TF + (i-TF)];
    }
    __syncthreads();
    const int sub = tid >> 7, col = tid & 127;
    float acc[4];
    const float b = bin[col];
    acc[0]=acc[1]=acc[2]=acc[3]=b;
    #pragma unroll 8
    for (int i = 0; i < 32; ++i) {
        const float wv = Win[i*HID + col];
        acc[0] = fmaf(sIn[sub][i],   wv, acc[0]);
        acc[1] = fmaf(sIn[2+sub][i], wv, acc[1]);
        acc[2] = fmaf(sIn[4+sub][i], wv, acc[2]);
        acc[3] = fmaf(sIn[6+sub][i], wv, acc[3]);
    }
    #pragma unroll
    for (int nn = 0; nn < 4; ++nn) {
        const size_t idx = (size_t)(blockIdx.x*8 + nn*2 + sub)*HID + col;
        hh[idx] = acc[nn];
        u16 hb = bf16_rn(acc[nn]);
        hhH[idx] = hb; hhL[idx] = bf16_rn(acc[nn] - bf16_tof(hb));
    }
}

// ---------------------------------------------------------------- edge (MFMA, LDS-A)
__global__ __launch_bounds__(256, 6) void edge_k(
    const u16* __restrict__ hhH, const u16* __restrict__ hhL,
    const float* __restrict__ x,
    const int* __restrict__ ecol, const int* __restrict__ tbond,
    const u16* __restrict__ tembH, const u16* __restrict__ tembL,
    const u16* __restrict__ W1TH, const u16* __restrict__ W1TL,
    const u16* __restrict__ W2TH, const u16* __restrict__ W2TL,
    const float* __restrict__ be1, const float* __restrict__ g1,
    const float* __restrict__ bt1, const float* __restrict__ be2,
    const float* __restrict__ Watt, const float* __restrict__ batt,
    u16* __restrict__ aggH, u16* __restrict__ aggL)
{
    // region layout (26624 B total):
    //  [0,8192)     sColH      | after GEMM1: sMid f32 [32][132] (16896B) | after LN: sB2H
    //  [8192,16384) sColL      |                                          | sB2L
    //  [16384,20480) sTailH    | (sMid tail)
    //  [20480,24576) sTailL
    //  [24576,26624) sHHb (H 512 u16 | L 512 u16)  | after GEMM2: sAP(512B)+sAttv(128B)
    __shared__ __align__(16) char smem[26624];
    u16*   sColH = (u16*)(smem);
    u16*   sColL = (u16*)(smem + 8192);
    u16*   sTailH= (u16*)(smem + 16384);
    u16*   sTailL= (u16*)(smem + 20480);
    u16*   sHHb  = (u16*)(smem + 24576);
    float* sMid  = (float*)(smem);
    u16*   sB2H  = (u16*)(smem);
    u16*   sB2L  = (u16*)(smem + 8192);
    float* sAP   = (float*)(smem + 24576);
    float* sAttv = (float*)(smem + 25088);

    const int tid = threadIdx.x;
    const int node0 = blockIdx.x * NPB;
    const int w = tid >> 6, lane = tid & 63, lr = lane & 15, lh = lane >> 4;
    const int colB0 = w*32 + lr, colB1 = colB0 + 16;

    // ---- phase A: tail chunks [32 rows][8 chunks of 8]: temb(2)|smear(3)|zero(3)
    {
        const int row = tid & 31, part = tid >> 5;
        U8 vh, vl;
        if (part < 2) {
            const int r = node0 + (row >> 3);
            const int c = ecol[node0*KNN + row];
            int sbi = r*(KAT-1) + c - (r/KAT)*KAT - (r < c ? 1 : 0);
            const int tb = tbond[sbi];
            #pragma unroll
            for (int j = 0; j < 8; ++j) {
                vh.a[j] = tembH[tb*TF + part*8 + j];
                vl.a[j] = tembL[tb*TF + part*8 + j];
            }
        } else if (part < 5) {
            const int r = node0 + (row >> 3);
            const int c = ecol[node0*KNN + row];
            float dx = x[3*r]-x[3*c], dy = x[3*r+1]-x[3*c+1], dz = x[3*r+2]-x[3*c+2];
            float dist = fminf(sqrtf(dx*dx+dy*dy+dz*dz), 4.0f);
            const float Cc = 0.12220674183617694f;   // log2(5)/19
            #pragma unroll
            for (int j = 0; j < 8; ++j) {
                int g = (part-2)*8 + j;
                float v = 0.0f;
                if (g < NG) {
                    float og = exp2f(Cc*(float)g) - 1.0f;
                    int gm = (g > 0) ? g : 1;
                    float d = exp2f(Cc*(float)gm) - exp2f(Cc*(float)(gm-1));
                    float dd = dist - og;
                    v = __expf(-0.5f/(d*d)*dd*dd);
                }
                u16 hb = bf16_rn(v); vh.a[j] = hb; vl.a[j] = bf16_rn(v - bf16_tof(hb));
            }
        } else {
            #pragma unroll
            for (int j = 0; j < 8; ++j) { vh.a[j] = 0; vl.a[j] = 0; }
        }
        const int cs = (part ^ (row & 7)) << 3;
        *(bfx8*)&sTailH[row*64 + cs] = vh.v;
        *(bfx8*)&sTailL[row*64 + cs] = vl.v;
    }

    // ---- stage col-hh (coalesced 256B rows, swizzled chunks) -----------
    // NOTE: swizzle key must be (e & 15): chunk index is 4 bits. Using full
    // 5-bit e overflowed the row slot for e>=16 (round-4 NaN bug).
    for (int idx = tid; idx < 1024; idx += 256) {
        const int e  = (idx >> 4) & 31;
        const int c4 = idx & 15;
        const int hl = idx >> 9;
        const int c  = ecol[node0*KNN + e];
        const bfx8 v = *(const bfx8*)((hl ? hhL : hhH) + (size_t)c*HID + c4*8);
        u16* dst = hl ? sColL : sColH;
        *(bfx8*)&dst[e*128 + ((c4 ^ (e & 15)) << 3)] = v;
    }
    // ---- stage own-row hh ----------------------------------------------
    if (tid < 128) {
        const int hl = tid >> 6, n = (tid >> 4) & 3, c4 = tid & 15;
        const bfx8 v = *(const bfx8*)((hl ? hhL : hhH) + (size_t)(node0+n)*HID + c4*8);
        *(bfx8*)&sHHb[hl*512 + n*128 + c4*8] = v;
    }
    __syncthreads();                                    // bar1

    // ---- GEMM1: [32 x 320] @ [320 x 128], W prefetch 1 step ahead ------
    const u16* bH0 = W1TH + (size_t)colB0*K1 + lh*8;
    const u16* bH1 = W1TH + (size_t)colB1*K1 + lh*8;
    const u16* bL0 = W1TL + (size_t)colB0*K1 + lh*8;
    const u16* bL1 = W1TL + (size_t)colB1*K1 + lh*8;

    f32x4 acc00={0,0,0,0}, acc01={0,0,0,0}, acc10={0,0,0,0}, acc11={0,0,0,0};
    {
        const int rbase0 = (lr >> 3)*128 + lh*8;
        const int rbase1 = (2 + (lr >> 3))*128 + lh*8;
        bfx8 wh0 = *(const bfx8*)bH0, wh1 = *(const bfx8*)bH1;
        bfx8 wl0 = *(const bfx8*)bL0, wl1 = *(const bfx8*)bL1;
        #pragma unroll
        for (int s = 0; s < 10; ++s) {
            bfx8 nh0 = wh0, nh1 = wh1, nl0 = wl0, nl1 = wl1;
            if (s < 9) {
                nh0 = *(const bfx8*)(bH0 + 32*(s+1)); nh1 = *(const bfx8*)(bH1 + 32*(s+1));
                nl0 = *(const bfx8*)(bL0 + 32*(s+1)); nl1 = *(const bfx8*)(bL1 + 32*(s+1));
            }
            bfx8 ah0, ah1, al0, al1;
            if (s < 4) {
                ah0 = *(const bfx8*)&sHHb[rbase0 + 32*s];
                ah1 = *(const bfx8*)&sHHb[rbase1 + 32*s];
                al0 = *(const bfx8*)&sHHb[512 + rbase0 + 32*s];
                al1 = *(const bfx8*)&sHHb[512 + rbase1 + 32*s];
            } else if (s < 8) {
                const int c4 = (s-4)*4 + lh;
                const int i0 = lr*128 + ((c4 ^ lr) << 3);
                const int i1 = (16+lr)*128 + ((c4 ^ lr) << 3);
                ah0 = *(const bfx8*)&sColH[i0]; ah1 = *(const bfx8*)&sColH[i1];
                al0 = *(const bfx8*)&sColL[i0]; al1 = *(const bfx8*)&sColL[i1];
            } else {
                const int c4 = (s-8)*4 + lh;
                const int i0 = lr*64 + ((c4 ^ (lr & 7)) << 3);
                const int i1 = (16+lr)*64 + ((c4 ^ (lr & 7)) << 3);
                ah0 = *(const bfx8*)&sTailH[i0]; ah1 = *(const bfx8*)&sTailH[i1];
                al0 = *(const bfx8*)&sTailL[i0]; al1 = *(const bfx8*)&sTailL[i1];
            }
            acc00 = mfma3(ah0, al0, wh0, wl0, acc00);
            acc01 = mfma3(ah0, al0, wh1, wl1, acc01);
            acc10 = mfma3(ah1, al1, wh0, wl0, acc10);
            acc11 = mfma3(ah1, al1, wh1, wl1, acc11);
            wh0 = nh0; wh1 = nh1; wl0 = nl0; wl1 = nl1;
        }
    }
    __syncthreads();                                    // bar2 (A reads done)

    // ---- C1 + bias -> sMid ---------------------------------------------
    {
        const float b10 = be1[colB0], b11 = be1[colB1];
        #pragma unroll
        for (int j = 0; j < 4; ++j) {
            const int r0 = 4*lh + j;
            sMid[r0*MIDSTR + colB0]      = acc00[j] + b10;
            sMid[r0*MIDSTR + colB1]      = acc01[j] + b11;
            sMid[(16+r0)*MIDSTR + colB0] = acc10[j] + b10;
            sMid[(16+r0)*MIDSTR + colB1] = acc11[j] + b11;
        }
    }
    __syncthreads();                                    // bar3

    // ---- LayerNorm + SiLU (regs) ---------------------------------------
    float y[16];
    const int eLN = tid >> 3, c0 = (tid & 7)*16;
    {
        const float* mrow = &sMid[eLN*MIDSTR + c0];
        float4 v0 = *(const float4*)&mrow[0];
        float4 v1 = *(const float4*)&mrow[4];
        float4 v2 = *(const float4*)&mrow[8];
        float4 v3 = *(const float4*)&mrow[12];
        float s = v0.x+v0.y+v0.z+v0.w + v1.x+v1.y+v1.z+v1.w
                + v2.x+v2.y+v2.z+v2.w + v3.x+v3.y+v3.z+v3.w;
        float q = v0.x*v0.x+v0.y*v0.y+v0.z*v0.z+v0.w*v0.w
                + v1.x*v1.x+v1.y*v1.y+v1.z*v1.z+v1.w*v1.w
                + v2.x*v2.x+v2.y*v2.y+v2.z*v2.z+v2.w*v2.w
                + v3.x*v3.x+v3.y*v3.y+v3.z*v3.z+v3.w*v3.w;
        #pragma unroll
        for (int m = 4; m >= 1; m >>= 1) { s += __shfl_xor(s, m); q += __shfl_xor(q, m); }
        float mu  = s * (1.0f/HID);
        float var = q * (1.0f/HID) - mu*mu;
        float inv = rsqrtf(var + 1e-5f);
        const float4 G0 = *(const float4*)&g1[c0+0],  G1v = *(const float4*)&g1[c0+4];
        const float4 G2 = *(const float4*)&g1[c0+8],  G3 = *(const float4*)&g1[c0+12];
        const float4 B0 = *(const float4*)&bt1[c0+0], B1 = *(const float4*)&bt1[c0+4];
        const float4 B2 = *(const float4*)&bt1[c0+8], B3 = *(const float4*)&bt1[c0+12];
        y[0]=siluf(fmaf((v0.x-mu)*inv,G0.x,B0.x));  y[1]=siluf(fmaf((v0.y-mu)*inv,G0.y,B0.y));
        y[2]=siluf(fmaf((v0.z-mu)*inv,G0.z,B0.z));  y[3]=siluf(fmaf((v0.w-mu)*inv,G0.w,B0.w));
        y[4]=siluf(fmaf((v1.x-mu)*inv,G1v.x,B1.x)); y[5]=siluf(fmaf((v1.y-mu)*inv,G1v.y,B1.y));
        y[6]=siluf(fmaf((v1.z-mu)*inv,G1v.z,B1.z)); y[7]=siluf(fmaf((v1.w-mu)*inv,G1v.w,B1.w));
        y[8]=siluf(fmaf((v2.x-mu)*inv,G2.x,B2.x));  y[9]=siluf(fmaf((v2.y-mu)*inv,G2.y,B2.y));
        y[10]=siluf(fmaf((v2.z-mu)*inv,G2.z,B2.z)); y[11]=siluf(fmaf((v2.w-mu)*inv,G2.w,B2.w));
        y[12]=siluf(fmaf((v3.x-mu)*inv,G3.x,B3.x)); y[13]=siluf(fmaf((v3.y-mu)*inv,G3.y,B3.y));
        y[14]=siluf(fmaf((v3.z-mu)*inv,G3.z,B3.z)); y[15]=siluf(fmaf((v3.w-mu)*inv,G3.w,B3.w));
    }
    __syncthreads();                                    // bar4 (sMid reads done)
    {
        U8 ha, hb2, la, lb2;
        #pragma unroll
        for (int j = 0; j < 8; ++j) {
            u16 t0 = bf16_rn(y[j]);   ha.a[j]  = t0; la.a[j]  = bf16_rn(y[j]   - bf16_tof(t0));
            u16 t1 = bf16_rn(y[8+j]); hb2.a[j] = t1; lb2.a[j] = bf16_rn(y[8+j] - bf16_tof(t1));
        }
        const int cA = (2*(tid & 7))     ^ (eLN & 15);
        const int cB = (2*(tid & 7) + 1) ^ (eLN & 15);
        *(bfx8*)&sB2H[eLN*128 + (cA << 3)] = ha.v;
        *(bfx8*)&sB2H[eLN*128 + (cB << 3)] = hb2.v;
        *(bfx8*)&sB2L[eLN*128 + (cA << 3)] = la.v;
        *(bfx8*)&sB2L[eLN*128 + (cB << 3)] = lb2.v;
    }
    __syncthreads();                                    // bar5

    // ---- GEMM2: [32 x 128] @ [128 x 128] -------------------------------
    f32x4 d00={0,0,0,0}, d01={0,0,0,0}, d10={0,0,0,0}, d11={0,0,0,0};
    {
        const u16* c2H0 = W2TH + (size_t)colB0*HID + lh*8;
        const u16* c2H1 = W2TH + (size_t)colB1*HID + lh*8;
        const u16* c2L0 = W2TL + (size_t)colB0*HID + lh*8;
        const u16* c2L1 = W2TL + (size_t)colB1*HID + lh*8;
        bfx8 wh0 = *(const bfx8*)c2H0, wh1 = *(const bfx8*)c2H1;
        bfx8 wl0 = *(const bfx8*)c2L0, wl1 = *(const bfx8*)c2L1;
        #pragma unroll
        for (int s = 0; s < 4; ++s) {
            bfx8 nh0 = wh0, nh1 = wh1, nl0 = wl0, nl1 = wl1;
            if (s < 3) {
                nh0 = *(const bfx8*)(c2H0 + 32*(s+1)); nh1 = *(const bfx8*)(c2H1 + 32*(s+1));
                nl0 = *(const bfx8*)(c2L0 + 32*(s+1)); nl1 = *(const bfx8*)(c2L1 + 32*(s+1));
            }
            const int c4 = s*4 + lh;
            const int i0 = lr*128 + ((c4 ^ lr) << 3);
            const int i1 = (16+lr)*128 + ((c4 ^ lr) << 3);
            bfx8 ah0 = *(const bfx8*)&sB2H[i0], ah1 = *(const bfx8*)&sB2H[i1];
            bfx8 al0 = *(const bfx8*)&sB2L[i0], al1 = *(const bfx8*)&sB2L[i1];
            d00 = mfma3(ah0, al0, wh0, wl0, d00);
            d01 = mfma3(ah0, al0, wh1, wl1, d01);
            d10 = mfma3(ah1, al1, wh0, wl0, d10);
            d11 = mfma3(ah1, al1, wh1, wl1, d11);
            wh0 = nh0; wh1 = nh1; wl0 = nl0; wl1 = nl1;
        }
    }

    // ---- SiLU + attention gate -----------------------------------------
    float m00[4], m01[4], m10[4], m11[4];
    {
        const float b20 = be2[colB0], b21 = be2[colB1];
        #pragma unroll
        for (int j = 0; j < 4; ++j) {
            m00[j] = siluf(d00[j] + b20); m01[j] = siluf(d01[j] + b21);
            m10[j] = siluf(d10[j] + b20); m11[j] = siluf(d11[j] + b21);
        }
    }
    {
        const float wa0 = Watt[colB0], wa1 = Watt[colB1];
        float p0[4], p1[4];
        #pragma unroll
        for (int j = 0; j < 4; ++j) {
            p0[j] = m00[j]*wa0 + m01[j]*wa1;
            p1[j] = m10[j]*wa0 + m11[j]*wa1;
        }
        #pragma unroll
        for (int msk = 1; msk < 16; msk <<= 1) {
            #pragma unroll
            for (int j = 0; j < 4; ++j) {
                p0[j] += __shfl_xor(p0[j], msk);
                p1[j] += __shfl_xor(p1[j], msk);
            }
        }
        if (lr == 0) {
            #pragma unroll
            for (int j = 0; j < 4; ++j) {
                sAP[w*32 + 4*lh + j]      = p0[j];
                sAP[w*32 + 16 + 4*lh + j] = p1[j];
            }
        }
    }
    __syncthreads();                                    // bar6
    if (tid < EPB)
        sAttv[tid] = sigf(sAP[tid] + sAP[32+tid] + sAP[64+tid] + sAP[96+tid] + batt[0]);
    __syncthreads();                                    // bar7

    // ---- gated aggregate -> aggH/aggL ----------------------------------
    {
        float s00 = 0.f, s01 = 0.f, s10 = 0.f, s11 = 0.f;
        #pragma unroll
        for (int j = 0; j < 4; ++j) {
            const float a0 = sAttv[4*lh + j];
            const float a1 = sAttv[16 + 4*lh + j];
            s00 += m00[j]*a0; s01 += m01[j]*a0;
            s10 += m10[j]*a1; s11 += m11[j]*a1;
        }
        s00 += __shfl_xor(s00, 16); s01 += __shfl_xor(s01, 16);
        s10 += __shfl_xor(s10, 16); s11 += __shfl_xor(s11, 16);
        if (lh == 0) {
            wragg(aggH, aggL, (size_t)(node0+0)*HID + colB0, s00*0.2f);
            wragg(aggH, aggL, (size_t)(node0+0)*HID + colB1, s01*0.2f);
            wragg(aggH, aggL, (size_t)(node0+2)*HID + colB0, s10*0.2f);
            wragg(aggH, aggL, (size_t)(node0+2)*HID + colB1, s11*0.2f);
        } else if (lh == 2) {
            wragg(aggH, aggL, (size_t)(node0+1)*HID + colB0, s00*0.2f);
            wragg(aggH, aggL, (size_t)(node0+1)*HID + colB1, s01*0.2f);
            wragg(aggH, aggL, (size_t)(node0+3)*HID + colB0, s10*0.2f);
            wragg(aggH, aggL, (size_t)(node0+3)*HID + colB1, s11*0.2f);
        }
    }
}

// ---------------------------------------------------------------- node (MFMA, 32 nodes/block)
__global__ __launch_bounds__(256, 6) void node_k(
    float* __restrict__ hh, u16* __restrict__ hhH, u16* __restrict__ hhL,
    const u16* __restrict__ aggH, const u16* __restrict__ aggL,
    const u16* __restrict__ B1H, const u16* __restrict__ B1L,
    const u16* __restrict__ B2H, const u16* __restrict__ B2L,
    const float* __restrict__ bn1, const float* __restrict__ g2,
    const float* __restrict__ bt2, const float* __restrict__ bn2)
{
    __shared__ __align__(16) char smem[16896];
    float* sMid = (float*)smem;
    u16* sYH = (u16*)smem;
    u16* sYL = (u16*)(smem + 8192);

    const int tid = threadIdx.x;
    const int node0 = blockIdx.x * 32;
    const int w = tid >> 6, lane = tid & 63, lr = lane & 15, lh = lane >> 4;
    const int colB0 = w*32 + lr, colB1 = colB0 + 16;

    // ---- GEMM_n1: [32 x 256] @ [256 x 128] (A from global, L1-resident)
    const u16* a1h0 = hhH  + (size_t)(node0+lr)*HID + lh*8;
    const u16* a1l0 = hhL  + (size_t)(node0+lr)*HID + lh*8;
    const u16* a2h0 = aggH + (size_t)(node0+lr)*HID + lh*8;
    const u16* a2l0 = aggL + (size_t)(node0+lr)*HID + lh*8;
    const u16* c1H0 = B1H + (size_t)colB0*256 + lh*8;
    const u16* c1H1 = B1H + (size_t)colB1*256 + lh*8;
    const u16* c1L0 = B1L + (size_t)colB0*256 + lh*8;
    const u16* c1L1 = B1L + (size_t)colB1*256 + lh*8;

    f32x4 acc00={0,0,0,0}, acc01={0,0,0,0}, acc10={0,0,0,0}, acc11={0,0,0,0};
    {
        bfx8 wh0 = *(const bfx8*)c1H0, wh1 = *(const bfx8*)c1H1;
        bfx8 wl0 = *(const bfx8*)c1L0, wl1 = *(const bfx8*)c1L1;
        #pragma unroll
        for (int s = 0; s < 8; ++s) {
            bfx8 nh0 = wh0, nh1 = wh1, nl0 = wl0, nl1 = wl1;
            if (s < 7) {
                nh0 = *(const bfx8*)(c1H0 + 32*(s+1)); nh1 = *(const bfx8*)(c1H1 + 32*(s+1));
                nl0 = *(const bfx8*)(c1L0 + 32*(s+1)); nl1 = *(const bfx8*)(c1L1 + 32*(s+1));
            }
            bfx8 ah0, ah1, al0, al1;
            if (s < 4) {
                ah0 = *(const bfx8*)(a1h0 + 32*s);            ah1 = *(const bfx8*)(a1h0 + 16*HID + 32*s);
                al0 = *(const bfx8*)(a1l0 + 32*s);            al1 = *(const bfx8*)(a1l0 + 16*HID + 32*s);
            } else {
                ah0 = *(const bfx8*)(a2h0 + 32*(s-4));        ah1 = *(const bfx8*)(a2h0 + 16*HID + 32*(s-4));
                al0 = *(const bfx8*)(a2l0 + 32*(s-4));        al1 = *(const bfx8*)(a2l0 + 16*HID + 32*(s-4));
            }
            acc00 = mfma3(ah0, al0, wh0, wl0, acc00);
            acc01 = mfma3(ah0, al0, wh1, wl1, acc01);
            acc10 = mfma3(ah1, al1, wh0, wl0, acc10);
            acc11 = mfma3(ah1, al1, wh1, wl1, acc11);
            wh0 = nh0; wh1 = nh1; wl0 = nl0; wl1 = nl1;
        }
    }
    {
        const float b10 = bn1[colB0], b11 = bn1[colB1];
        #pragma unroll
        for (int j = 0; j < 4; ++j) {
            const int r0 = 4*lh + j;
            sMid[r0*MIDSTR + colB0]      = acc00[j] + b10;
            sMid[r0*MIDSTR + colB1]      = acc01[j] + b11;
            sMid[(16+r0)*MIDSTR + colB0] = acc10[j] + b10;
            sMid[(16+r0)*MIDSTR + colB1] = acc11[j] + b11;
        }
    }
    __syncthreads();

    // ---- LayerNorm + SiLU ----------------------------------------------
    float y[16];
    const int eLN = tid >> 3, c0 = (tid & 7)*16;
    {
        const float* mrow = &sMid[eLN*MIDSTR + c0];
        float4 v0 = *(const float4*)&mrow[0];
        float4 v1 = *(const float4*)&mrow[4];
        float4 v2 = *(const float4*)&mrow[8];
        float4 v3 = *(const float4*)&mrow[12];
        float s = v0.x+v0.y+v0.z+v0.w + v1.x+v1.y+v1.z+v1.w
                + v2.x+v2.y+v2.z+v2.w + v3.x+v3.y+v3.z+v3.w;
        float q = v0.x*v0.x+v0.y*v0.y+v0.z*v0.z+v0.w*v0.w
                + v1.x*v1.x+v1.y*v1.y+v1.z*v1.z+v1.w*v1.w
                + v2.x*v2.x+v2.y*v2.y+v2.z*v2.z+v2.w*v2.w
                + v3.x*v3.x+v3.y*v3.y+v3.z*v3.z+v3.w*v3.w;
        #pragma unroll
        for (int m = 4; m >= 1; m >>= 1) { s += __shfl_xor(s, m); q += __shfl_xor(q, m); }
        float mu  = s * (1.0f/HID);
        float var = q * (1.0f/HID) - mu*mu;
        float inv = rsqrtf(var + 1e-5f);
        const float4 G0 = *(const float4*)&g2[c0+0],  G1v = *(const float4*)&g2[c0+4];
        const float4 G2 = *(const float4*)&g2[c0+8],  G3 = *(const float4*)&g2[c0+12];
        const float4 B0 = *(const float4*)&bt2[c0+0], B1 = *(const float4*)&bt2[c0+4];
        const float4 B2 = *(const float4*)&bt2[c0+8], B3 = *(const float4*)&bt2[c0+12];
        y[0]=siluf(fmaf((v0.x-mu)*inv,G0.x,B0.x));  y[1]=siluf(fmaf((v0.y-mu)*inv,G0.y,B0.y));
        y[2]=siluf(fmaf((v0.z-mu)*inv,G0.z,B0.z));  y[3]=siluf(fmaf((v0.w-mu)*inv,G0.w,B0.w));
        y[4]=siluf(fmaf((v1.x-mu)*inv,G1v.x,B1.x)); y[5]=siluf(fmaf((v1.y-mu)*inv,G1v.y,B1.y));
        y[6]=siluf(fmaf((v1.z-mu)*inv,G1v.z,B1.z)); y[7]=siluf(fmaf((v1.w-mu)*inv,G1v.w,B1.w));
        y[8]=siluf(fmaf((v2.x-mu)*inv,G2.x,B2.x));  y[9]=siluf(fmaf((v2.y-mu)*inv,G2.y,B2.y));
        y[10]=siluf(fmaf((v2.z-mu)*inv,G2.z,B2.z)); y[11]=siluf(fmaf((v2.w-mu)*inv,G2.w,B2.w));
        y[12]=siluf(fmaf((v3.x-mu)*inv,G3.x,B3.x)); y[13]=siluf(fmaf((v3.y-mu)*inv,G3.y,B3.y));
        y[14]=siluf(fmaf((v3.z-mu)*inv,G3.z,B3.z)); y[15]=siluf(fmaf((v3.w-mu)*inv,G3.w,B3.w));
    }
    __syncthreads();
    {
        U8 ha, hb2, la, lb2;
        #pragma unroll
        for (int j = 0; j < 8; ++j) {
            u16 t0 = bf16_rn(y[j]);   ha.a[j]  = t0; la.a[j]  = bf16_rn(y[j]   - bf16_tof(t0));
            u16 t1 = bf16_rn(y[8+j]); hb2.a[j] = t1; lb2.a[j] = bf16_rn(y[8+j] - bf16_tof(t1));
        }
        const int cA = (2*(tid & 7))     ^ (eLN & 15);
        const int cB = (2*(tid & 7) + 1) ^ (eLN & 15);
        *(bfx8*)&sYH[eLN*128 + (cA << 3)] = ha.v;
        *(bfx8*)&sYH[eLN*128 + (cB << 3)] = hb2.v;
        *(bfx8*)&sYL[eLN*128 + (cA << 3)] = la.v;
        *(bfx8*)&sYL[eLN*128 + (cB << 3)] = lb2.v;
    }
    __syncthreads();

    // ---- GEMM_n2: [32 x 128] @ [128 x 128] -----------------------------
    f32x4 d00={0,0,0,0}, d01={0,0,0,0}, d10={0,0,0,0}, d11={0,0,0,0};
    {
        const u16* c2H0 = B2H + (size_t)colB0*HID + lh*8;
        const u16* c2H1 = B2H + (size_t)colB1*HID + lh*8;
        const u16* c2L0 = B2L + (size_t)colB0*HID + lh*8;
        const u16* c2L1 = B2L + (size_t)colB1*HID + lh*8;
        bfx8 wh0 = *(const bfx8*)c2H0, wh1 = *(const bfx8*)c2H1;
        bfx8 wl0 = *(const bfx8*)c2L0, wl1 = *(const bfx8*)c2L1;
        #pragma unroll
        for (int s = 0; s < 4; ++s) {
            bfx8 nh0 = wh0, nh1 = wh1, nl0 = wl0, nl1 = wl1;
            if (s < 3) {
                nh0 = *(const bfx8*)(c2H0 + 32*(s+1)); nh1 = *(const bfx8*)(c2H1 + 32*(s+1));
                nl0 = *(const bfx8*)(c2L0 + 32*(s+1)); nl1 = *(const bfx8*)(c2L1 + 32*(s+1));
            }
            const int c4 = s*4 + lh;
            const int i0 = lr*128 + ((c4 ^ lr) << 3);
            const int i1 = (16+lr)*128 + ((c4 ^ lr) << 3);
            bfx8 ah0 = *(const bfx8*)&sYH[i0], ah1 = *(const bfx8*)&sYH[i1];
            bfx8 al0 = *(const bfx8*)&sYL[i0], al1 = *(const bfx8*)&sYL[i1];
            d00 = mfma3(ah0, al0, wh0, wl0, d00);
            d01 = mfma3(ah0, al0, wh1, wl1, d01);
            d10 = mfma3(ah1, al1, wh0, wl0, d10);
            d11 = mfma3(ah1, al1, wh1, wl1, d11);
            wh0 = nh0; wh1 = nh1; wl0 = nl0; wl1 = nl1;
        }
    }

    // ---- bias + residual + write ---------------------------------------
    {
        const float b20 = bn2[colB0], b21 = bn2[colB1];
        #pragma unroll
        for (int j = 0; j < 4; ++j) {
            const int r0 = 4*lh + j, r1 = 16 + 4*lh + j;
            const size_t i00 = (size_t)(node0+r0)*HID + colB0;
            const size_t i01 = (size_t)(node0+r0)*HID + colB1;
            const size_t i10 = (size_t)(node0+r1)*HID + colB0;
            const size_t i11 = (size_t)(node0+r1)*HID + colB1;
            float v00 = hh[i00] + d00[j] + b20;
            float v01 = hh[i01] + d01[j] + b21;
            float v10 = hh[i10] + d10[j] + b20;
            float v11 = hh[i11] + d11[j] + b21;
            hh[i00] = v00; hh[i01] = v01; hh[i10] = v10; hh[i11] = v11;
            u16 h00 = bf16_rn(v00); hhH[i00] = h00; hhL[i00] = bf16_rn(v00 - bf16_tof(h00));
            u16 h01 = bf16_rn(v01); hhH[i01] = h01; hhL[i01] = bf16_rn(v01 - bf16_tof(h01));
            u16 h10 = bf16_rn(v10); hhH[i10] = h10; hhL[i10] = bf16_rn(v10 - bf16_tof(h10));
            u16 h11 = bf16_rn(v11); hhH[i11] = h11; hhL[i11] = bf16_rn(v11 - bf16_tof(h11));
        }
    }
}

// ---------------------------------------------------------------- output head
__global__ __launch_bounds__(HID) void out_k(
    const float* __restrict__ hh, const float* __restrict__ Woe,
    const float* __restrict__ boe, const float* __restrict__ Wf,
    const float* __restrict__ bf, float* __restrict__ out)
{
    __shared__ float sH[HID];
    const int lig = blockIdx.x, tid = threadIdx.x;
    float s = 0.0f;
    const float* base = hh + (size_t)lig*KAT*HID + tid;
    #pragma unroll 8
    for (int a = 0; a < KAT; ++a) s += base[a*HID];
    sH[tid] = s * (1.0f/KAT);
    __syncthreads();

    float contrib = 0.0f;
    if (tid < OUTF) {
        float p = boe[tid];
        #pragma unroll 4
        for (int i = 0; i < HID; ++i)
            p = fmaf(sH[i], Woe[i*OUTF + tid], p);
        contrib = p * Wf[tid];
    }
    #pragma unroll
    for (int m = 1; m < 64; m <<= 1) contrib += __shfl_xor(contrib, m);
    if (tid == 0) out[lig] = contrib + bf[0];
}

// ---------------------------------------------------------------- launch
extern "C" void kernel_launch(void* const* d_in, const int* in_sizes, int n_in,
                              void* d_out, int out_size, void* d_ws, size_t ws_size,
                              hipStream_t stream)
{
    (void)in_sizes; (void)n_in; (void)out_size; (void)ws_size;
    const float* x    = (const float*)d_in[0];
    const float* h    = (const float*)d_in[1];
    const int*   t    = (const int*)d_in[2];
    const int*   edges= (const int*)d_in[3];
    const int*   tb   = (const int*)d_in[4];
    const float* temb = (const float*)d_in[8];
    const float* Win  = (const float*)d_in[9];
    const float* bin  = (const float*)d_in[10];
    const float* We1  = (const float*)d_in[11];
    const float* be1  = (const float*)d_in[12];
    const float* g1   = (const float*)d_in[13];
    const float* bt1  = (const float*)d_in[14];
    const float* We2  = (const float*)d_in[15];
    const float* be2  = (const float*)d_in[16];
    const float* Watt = (const float*)d_in[17];
    const float* batt = (const float*)d_in[18];
    const float* Wn1  = (const float*)d_in[19];
    const float* bn1  = (const float*)d_in[20];
    const float* g2   = (const float*)d_in[21];
    const float* bt2  = (const float*)d_in[22];
    const float* Wn2  = (const float*)d_in[23];
    const float* bn2  = (const float*)d_in[24];
    const float* Woe  = (const float*)d_in[25];
    const float* boe  = (const float*)d_in[26];
    const float* Wf   = (const float*)d_in[27];
    const float* bf   = (const float*)d_in[28];
    float* out = (float*)d_out;

    char* wsb = (char*)d_ws;
    float* hh  = (float*)(wsb);                        // 16 MB
    u16* hhH   = (u16*)(wsb + ((size_t)16<<20));       // 8 MB
    u16* hhL   = (u16*)(wsb + ((size_t)24<<20));       // 8 MB
    u16* aggH  = (u16*)(wsb + ((size_t)32<<20));       // 8 MB
    u16* aggL  = (u16*)(wsb + ((size_t)40<<20));       // 8 MB
    u16* tembH = (u16*)(wsb + ((size_t)48<<20));
    u16* tembL = tembH + PREP_TEMB;
    u16* W1TH  = tembL + PREP_TEMB;
    u16* W1TL  = W1TH + PREP_W1;
    u16* W2TH  = W1TL + PREP_W1;
    u16* W2TL  = W2TH + PREP_W2;
    u16* WN1TH = W2TL + PREP_W2;
    u16* WN1TL = WN1TH + PREP_WN1;
    u16* WN2TH = WN1TL + PREP_WN1;
    u16* WN2TL = WN2TH + PREP_WN2;

    prep_k<<<(PREP_TOT + 255)/256, 256, 0, stream>>>(
        temb, We1, We2, Wn1, Wn2,
        tembH, tembL, W1TH, W1TL, W2TH, W2TL, WN1TH, WN1TL, WN2TH, WN2TL);

    embed_k<<<NNODES/8, 256, 0, stream>>>(h, t, temb, Win, bin, hh, hhH, hhL);

    for (int l = 0; l < 4; ++l) {
        edge_k<<<NNODES/NPB, 256, 0, stream>>>(
            hhH, hhL, x, edges + NEDGES, tb, tembH, tembL,
            W1TH + (size_t)l*128*K1, W1TL + (size_t)l*128*K1,
            W2TH + (size_t)l*128*128, W2TL + (size_t)l*128*128,
            be1 + l*HID, g1 + l*HID, bt1 + l*HID, be2 + l*HID,
            Watt + l*HID, batt + l, aggH, aggL);
        node_k<<<NNODES/32, 256, 0, stream>>>(
            hh, hhH, hhL, aggH, aggL,
            WN1TH + (size_t)l*128*256, WN1TL + (size_t)l*128*256,
            WN2TH + (size_t)l*128*128, WN2TL + (size_t)l*128*128,
            bn1 + l*HID, g2 + l*HID, bt2 + l*HID, bn2 + l*HID);
    }
    out_k<<<NLIG, HID, 0, stream>>>(hh, Woe, boe, Wf, bf, out);
}

// Round 6
// 819.736 us; speedup vs baseline: 4.5983x; 1.3730x over previous
//
#include <hip/hip_runtime.h>
#include <math.h>

#define NNODES 32768
#define NLIG   1024
#define KAT    32
#define KNN    8
#define NEDGES (NNODES*KNN)
#define HID    128
#define TF     16
#define NG     20
#define OUTF   64

#define NPB    8            // nodes per edge-block
#define EPB    64           // edges per edge-block
#define K1     320          // padded GEMM1 K (292 -> 320)
#define MIDSTR 132          // sMid row stride (floats)

typedef unsigned short u16;
typedef __attribute__((__ext_vector_type__(8))) short bfx8;
typedef __attribute__((__ext_vector_type__(4))) float f32x4;

union U8 { u16 a[8]; bfx8 v; };

__device__ __forceinline__ float siluf(float v) {
    return __fdividef(v, 1.0f + __expf(-v));
}
__device__ __forceinline__ float sigf(float v) {
    return __fdividef(1.0f, 1.0f + __expf(-v));
}
__device__ __forceinline__ u16 bf16_rn(float f) {
    union { float f; unsigned u; } v; v.f = f;
    unsigned r = v.u + 0x7FFFu + ((v.u >> 16) & 1u);
    return (u16)(r >> 16);
}
__device__ __forceinline__ float bf16_tof(u16 u) {
    union { unsigned u; float f; } v; v.u = ((unsigned)u) << 16;
    return v.f;
}
__device__ __forceinline__ f32x4 mfma3(bfx8 ah, bfx8 al, bfx8 wh, bfx8 wl, f32x4 c) {
    c = __builtin_amdgcn_mfma_f32_16x16x32_bf16(ah, wh, c, 0, 0, 0);
    c = __builtin_amdgcn_mfma_f32_16x16x32_bf16(ah, wl, c, 0, 0, 0);
    c = __builtin_amdgcn_mfma_f32_16x16x32_bf16(al, wh, c, 0, 0, 0);
    return c;
}
__device__ __forceinline__ void wragg(u16* __restrict__ H, u16* __restrict__ L,
                                      size_t i, float v) {
    u16 hb = bf16_rn(v);
    H[i] = hb; L[i] = bf16_rn(v - bf16_tof(hb));
}

// ---------------------------------------------------------------- prep
#define PREP_TEMB 16000
#define PREP_W1   (4*128*K1)       // 163840
#define PREP_W2   (4*128*128)      // 65536
#define PREP_WN1  (4*128*256)      // 131072
#define PREP_WN2  (4*128*128)      // 65536
#define PREP_TOT  (PREP_TEMB+PREP_W1+PREP_W2+PREP_WN1+PREP_WN2)

__global__ __launch_bounds__(256) void prep_k(
    const float* __restrict__ temb, const float* __restrict__ We1,
    const float* __restrict__ We2,  const float* __restrict__ Wn1,
    const float* __restrict__ Wn2,
    u16* __restrict__ tembH, u16* __restrict__ tembL,
    u16* __restrict__ W1TH, u16* __restrict__ W1TL,
    u16* __restrict__ W2TH, u16* __restrict__ W2TL,
    u16* __restrict__ WN1TH, u16* __restrict__ WN1TL,
    u16* __restrict__ WN2TH, u16* __restrict__ WN2TL)
{
    int i = blockIdx.x*256 + threadIdx.x;
    if (i >= PREP_TOT) return;
    float v; u16 *dh, *dl; int di;
    if (i < PREP_TEMB) {
        v = temb[i]; dh = tembH; dl = tembL; di = i;
    } else if (i < PREP_TEMB + PREP_W1) {
        int j = i - PREP_TEMB; di = j; dh = W1TH; dl = W1TL;
        int l = j / (128*K1); int r = j - l*(128*K1);
        int col = r / K1, k = r - col*K1;
        v = (k < 292) ? We1[(size_t)l*292*128 + (size_t)k*128 + col] : 0.0f;
    } else if (i < PREP_TEMB + PREP_W1 + PREP_W2) {
        int j = i - PREP_TEMB - PREP_W1; di = j; dh = W2TH; dl = W2TL;
        int l = j >> 14; int r = j & 16383;
        int col = r >> 7, k = r & 127;
        v = We2[(size_t)l*16384 + (size_t)k*128 + col];
    } else if (i < PREP_TEMB + PREP_W1 + PREP_W2 + PREP_WN1) {
        int j = i - PREP_TEMB - PREP_W1 - PREP_W2; di = j; dh = WN1TH; dl = WN1TL;
        int l = j >> 15; int r = j & 32767;
        int col = r >> 8, k = r & 255;
        v = Wn1[(size_t)l*32768 + (size_t)k*128 + col];
    } else {
        int j = i - PREP_TEMB - PREP_W1 - PREP_W2 - PREP_WN1; di = j; dh = WN2TH; dl = WN2TL;
        int l = j >> 14; int r = j & 16383;
        int col = r >> 7, k = r & 127;
        v = Wn2[(size_t)l*16384 + (size_t)k*128 + col];
    }
    u16 hb = bf16_rn(v);
    dh[di] = hb;
    dl[di] = bf16_rn(v - bf16_tof(hb));
}

// ---------------------------------------------------------------- embed (8 nodes/block)
__global__ __launch_bounds__(256) void embed_k(
    const float* __restrict__ h, const int* __restrict__ t,
    const float* __restrict__ temb, const float* __restrict__ Win,
    const float* __restrict__ bin, float* __restrict__ hh,
    u16* __restrict__ hhH, u16* __restrict__ hhL)
{
    __shared__ float sIn[8][32];
    const int tid = threadIdx.x;
    {
        const int n = tid >> 5, i = tid & 31;
        const int node = blockIdx.x*8 + n;
        sIn[n][i] = (i < TF) ? h[node*TF + i] : temb[t[node]*TF + (i-TF)];
    }
    __syncthreads();
    const int sub = tid >> 7, col = tid & 127;
    float acc[4];
    const float b = bin[col];
    acc[0]=acc[1]=acc[2]=acc[3]=b;
    #pragma unroll 8
    for (int i = 0; i < 32; ++i) {
        const float wv = Win[i*HID + col];
        acc[0] = fmaf(sIn[sub][i],   wv, acc[0]);
        acc[1] = fmaf(sIn[2+sub][i], wv, acc[1]);
        acc[2] = fmaf(sIn[4+sub][i], wv, acc[2]);
        acc[3] = fmaf(sIn[6+sub][i], wv, acc[3]);
    }
    #pragma unroll
    for (int nn = 0; nn < 4; ++nn) {
        const size_t idx = (size_t)(blockIdx.x*8 + nn*2 + sub)*HID + col;
        hh[idx] = acc[nn];
        u16 hb = bf16_rn(acc[nn]);
        hhH[idx] = hb; hhL[idx] = bf16_rn(acc[nn] - bf16_tof(hb));
    }
}

// ---------------------------------------------------------------- edge (MFMA, M=64, ligand-table)
__global__ __launch_bounds__(256, 4) void edge_k(
    const u16* __restrict__ hhH, const u16* __restrict__ hhL,
    const float* __restrict__ x,
    const int* __restrict__ ecol, const int* __restrict__ tbond,
    const u16* __restrict__ tembH, const u16* __restrict__ tembL,
    const u16* __restrict__ W1TH, const u16* __restrict__ W1TL,
    const u16* __restrict__ W2TH, const u16* __restrict__ W2TL,
    const float* __restrict__ be1, const float* __restrict__ g1,
    const float* __restrict__ bt1, const float* __restrict__ be2,
    const float* __restrict__ Watt, const float* __restrict__ batt,
    u16* __restrict__ aggH, u16* __restrict__ aggL)
{
    // LDS lifetimes:
    //  phase1 (staging+GEMM1): tblH[0,8K) tblL[8K,16K) tailH[16K,24K) tailL[24K,32K)
    //  phase2 (sMid+LN):       sMid f32 [0, 33792) aliases all of the above
    //  phase3 (sB2+GEMM2):     sB2H[0,16K) sB2L[16K,32K) aliases sMid
    //  phase4: sAP [33792,34816), sAttv [34816,35072)
    __shared__ __align__(16) char smem[35072];
    u16*   tblH  = (u16*)(smem);
    u16*   tblL  = (u16*)(smem + 8192);
    u16*   tailH = (u16*)(smem + 16384);
    u16*   tailL = (u16*)(smem + 24576);
    float* sMid  = (float*)(smem);
    u16*   sB2H  = (u16*)(smem);
    u16*   sB2L  = (u16*)(smem + 16384);
    float* sAP   = (float*)(smem + 33792);
    float* sAttv = (float*)(smem + 34816);

    const int tid = threadIdx.x;
    const int node0 = blockIdx.x * NPB;
    const int ligBase = node0 & ~31;
    const int aBase   = node0 & 31;      // 0,8,16,24
    const int w = tid >> 6, lane = tid & 63, lr = lane & 15, lh = lane >> 4;
    const int colB0 = w*32 + lr, colB1 = colB0 + 16;

    // ---- per-lane col indices (local atom ids) -------------------------
    int aCol[4];
    #pragma unroll
    for (int rt = 0; rt < 4; ++rt)
        aCol[rt] = ecol[node0*KNN + rt*16 + lr] & 31;

    // ---- stage ligand hh table (32 atoms x 16 chunks, hi/lo) -----------
    for (int idx = tid; idx < 1024; idx += 256) {
        const int hl = idx >> 9, rem = idx & 511;
        const int a = rem >> 4, c4 = rem & 15;
        const bfx8 v = *(const bfx8*)((hl ? hhL : hhH) + (size_t)(ligBase + a)*HID + c4*8);
        u16* dst = hl ? tblL : tblH;
        *(bfx8*)&dst[a*128 + ((c4 ^ (a & 15)) << 3)] = v;
    }

    // ---- tail chunks [64 rows][8 chunks]: temb(2)|smear(3)|zero(3) -----
    for (int pe = tid; pe < 512; pe += 256) {
        const int row = pe & 63, part = pe >> 6;
        U8 vh, vl;
        if (part < 2) {
            const int r = node0 + (row >> 3);
            const int c = ecol[node0*KNN + row];
            int sbi = r*(KAT-1) + c - (r/KAT)*KAT - (r < c ? 1 : 0);
            const int tb = tbond[sbi];
            #pragma unroll
            for (int j = 0; j < 8; ++j) {
                vh.a[j] = tembH[tb*TF + part*8 + j];
                vl.a[j] = tembL[tb*TF + part*8 + j];
            }
        } else if (part < 5) {
            const int r = node0 + (row >> 3);
            const int c = ecol[node0*KNN + row];
            float dx = x[3*r]-x[3*c], dy = x[3*r+1]-x[3*c+1], dz = x[3*r+2]-x[3*c+2];
            float dist = fminf(sqrtf(dx*dx+dy*dy+dz*dz), 4.0f);
            const float Cc = 0.12220674183617694f;   // log2(5)/19
            #pragma unroll
            for (int j = 0; j < 8; ++j) {
                int g = (part-2)*8 + j;
                float v = 0.0f;
                if (g < NG) {
                    float og = exp2f(Cc*(float)g) - 1.0f;
                    int gm = (g > 0) ? g : 1;
                    float d = exp2f(Cc*(float)gm) - exp2f(Cc*(float)(gm-1));
                    float dd = dist - og;
                    v = __expf(-0.5f/(d*d)*dd*dd);
                }
                u16 hb = bf16_rn(v); vh.a[j] = hb; vl.a[j] = bf16_rn(v - bf16_tof(hb));
            }
        } else {
            #pragma unroll
            for (int j = 0; j < 8; ++j) { vh.a[j] = 0; vl.a[j] = 0; }
        }
        const int cs = (part ^ (row & 7)) << 3;
        *(bfx8*)&tailH[row*64 + cs] = vh.v;
        *(bfx8*)&tailL[row*64 + cs] = vl.v;
    }
    __syncthreads();                                    // bar1

    // ---- GEMM1: [64 x 320] @ [320 x 128], 1-deep W prefetch ------------
    const u16* bH0 = W1TH + (size_t)colB0*K1 + lh*8;
    const u16* bH1 = W1TH + (size_t)colB1*K1 + lh*8;
    const u16* bL0 = W1TL + (size_t)colB0*K1 + lh*8;
    const u16* bL1 = W1TL + (size_t)colB1*K1 + lh*8;

    f32x4 acc[4][2];
    #pragma unroll
    for (int rt = 0; rt < 4; ++rt) { acc[rt][0] = (f32x4){0,0,0,0}; acc[rt][1] = (f32x4){0,0,0,0}; }
    {
        bfx8 wh0 = *(const bfx8*)bH0, wh1 = *(const bfx8*)bH1;
        bfx8 wl0 = *(const bfx8*)bL0, wl1 = *(const bfx8*)bL1;
        #pragma unroll
        for (int s = 0; s < 10; ++s) {
            bfx8 nh0 = wh0, nh1 = wh1, nl0 = wl0, nl1 = wl1;
            if (s < 9) {
                nh0 = *(const bfx8*)(bH0 + 32*(s+1)); nh1 = *(const bfx8*)(bH1 + 32*(s+1));
                nl0 = *(const bfx8*)(bL0 + 32*(s+1)); nl1 = *(const bfx8*)(bL1 + 32*(s+1));
            }
            #pragma unroll
            for (int rt = 0; rt < 4; ++rt) {
                int ad;
                const u16 *pH, *pL;
                if (s < 4) {
                    const int aR = aBase + 2*rt + (lr >> 3);
                    const int c4 = s*4 + lh;
                    ad = aR*128 + ((c4 ^ (aR & 15)) << 3);
                    pH = tblH; pL = tblL;
                } else if (s < 8) {
                    const int aC = aCol[rt];
                    const int c4 = (s-4)*4 + lh;
                    ad = aC*128 + ((c4 ^ (aC & 15)) << 3);
                    pH = tblH; pL = tblL;
                } else {
                    const int r = rt*16 + lr;
                    const int c4 = (s-8)*4 + lh;
                    ad = r*64 + ((c4 ^ (r & 7)) << 3);
                    pH = tailH; pL = tailL;
                }
                const bfx8 ah = *(const bfx8*)&pH[ad];
                const bfx8 al = *(const bfx8*)&pL[ad];
                acc[rt][0] = mfma3(ah, al, wh0, wl0, acc[rt][0]);
                acc[rt][1] = mfma3(ah, al, wh1, wl1, acc[rt][1]);
            }
            wh0 = nh0; wh1 = nh1; wl0 = nl0; wl1 = nl1;
        }
    }
    __syncthreads();                                    // bar2 (tbl/tail reads done)

    // ---- C1 + bias -> sMid ---------------------------------------------
    {
        const float b10 = be1[colB0], b11 = be1[colB1];
        #pragma unroll
        for (int rt = 0; rt < 4; ++rt) {
            #pragma unroll
            for (int j = 0; j < 4; ++j) {
                const int row = rt*16 + 4*lh + j;
                sMid[row*MIDSTR + colB0] = acc[rt][0][j] + b10;
                sMid[row*MIDSTR + colB1] = acc[rt][1][j] + b11;
            }
        }
    }
    __syncthreads();                                    // bar3

    // ---- LayerNorm + SiLU (4 lanes/row, 32 cols each) ------------------
    float y[32];
    const int rowLN = tid >> 2, c0 = (tid & 3)*32;
    {
        const float* mrow = &sMid[rowLN*MIDSTR + c0];
        float s = 0.0f, q = 0.0f;
        #pragma unroll
        for (int i = 0; i < 8; ++i) {
            const float4 v = *(const float4*)&mrow[4*i];
            y[4*i+0] = v.x; y[4*i+1] = v.y; y[4*i+2] = v.z; y[4*i+3] = v.w;
            s += v.x + v.y + v.z + v.w;
            q += v.x*v.x + v.y*v.y + v.z*v.z + v.w*v.w;
        }
        s += __shfl_xor(s, 1); q += __shfl_xor(q, 1);
        s += __shfl_xor(s, 2); q += __shfl_xor(q, 2);
        const float mu  = s * (1.0f/HID);
        const float var = q * (1.0f/HID) - mu*mu;
        const float inv = rsqrtf(var + 1e-5f);
        #pragma unroll
        for (int i = 0; i < 8; ++i) {
            const float4 G = *(const float4*)&g1[c0 + 4*i];
            const float4 B = *(const float4*)&bt1[c0 + 4*i];
            y[4*i+0] = siluf(fmaf((y[4*i+0]-mu)*inv, G.x, B.x));
            y[4*i+1] = siluf(fmaf((y[4*i+1]-mu)*inv, G.y, B.y));
            y[4*i+2] = siluf(fmaf((y[4*i+2]-mu)*inv, G.z, B.z));
            y[4*i+3] = siluf(fmaf((y[4*i+3]-mu)*inv, G.w, B.w));
        }
    }
    __syncthreads();                                    // bar4 (sMid reads done)
    {
        #pragma unroll
        for (int cc = 0; cc < 4; ++cc) {
            U8 ph, pl;
            #pragma unroll
            for (int j = 0; j < 8; ++j) {
                const float v = y[cc*8 + j];
                u16 t0 = bf16_rn(v);
                ph.a[j] = t0; pl.a[j] = bf16_rn(v - bf16_tof(t0));
            }
            const int c4 = (tid & 3)*4 + cc;
            const int ad = rowLN*128 + ((c4 ^ (rowLN & 15)) << 3);
            *(bfx8*)&sB2H[ad] = ph.v;
            *(bfx8*)&sB2L[ad] = pl.v;
        }
    }
    __syncthreads();                                    // bar5

    // ---- GEMM2: [64 x 128] @ [128 x 128] -------------------------------
    f32x4 d[4][2];
    #pragma unroll
    for (int rt = 0; rt < 4; ++rt) { d[rt][0] = (f32x4){0,0,0,0}; d[rt][1] = (f32x4){0,0,0,0}; }
    {
        const u16* c2H0 = W2TH + (size_t)colB0*HID + lh*8;
        const u16* c2H1 = W2TH + (size_t)colB1*HID + lh*8;
        const u16* c2L0 = W2TL + (size_t)colB0*HID + lh*8;
        const u16* c2L1 = W2TL + (size_t)colB1*HID + lh*8;
        bfx8 wh0 = *(const bfx8*)c2H0, wh1 = *(const bfx8*)c2H1;
        bfx8 wl0 = *(const bfx8*)c2L0, wl1 = *(const bfx8*)c2L1;
        #pragma unroll
        for (int s = 0; s < 4; ++s) {
            bfx8 nh0 = wh0, nh1 = wh1, nl0 = wl0, nl1 = wl1;
            if (s < 3) {
                nh0 = *(const bfx8*)(c2H0 + 32*(s+1)); nh1 = *(const bfx8*)(c2H1 + 32*(s+1));
                nl0 = *(const bfx8*)(c2L0 + 32*(s+1)); nl1 = *(const bfx8*)(c2L1 + 32*(s+1));
            }
            #pragma unroll
            for (int rt = 0; rt < 4; ++rt) {
                const int r = rt*16 + lr;
                const int c4 = s*4 + lh;
                const int ad = r*128 + ((c4 ^ (r & 15)) << 3);
                const bfx8 ah = *(const bfx8*)&sB2H[ad];
                const bfx8 al = *(const bfx8*)&sB2L[ad];
                d[rt][0] = mfma3(ah, al, wh0, wl0, d[rt][0]);
                d[rt][1] = mfma3(ah, al, wh1, wl1, d[rt][1]);
            }
            wh0 = nh0; wh1 = nh1; wl0 = nl0; wl1 = nl1;
        }
    }

    // ---- SiLU + attention gate -----------------------------------------
    float m[4][2][4];
    {
        const float b20 = be2[colB0], b21 = be2[colB1];
        #pragma unroll
        for (int rt = 0; rt < 4; ++rt) {
            #pragma unroll
            for (int j = 0; j < 4; ++j) {
                m[rt][0][j] = siluf(d[rt][0][j] + b20);
                m[rt][1][j] = siluf(d[rt][1][j] + b21);
            }
        }
    }
    {
        const float wa0 = Watt[colB0], wa1 = Watt[colB1];
        float p[4][4];
        #pragma unroll
        for (int rt = 0; rt < 4; ++rt)
            #pragma unroll
            for (int j = 0; j < 4; ++j)
                p[rt][j] = m[rt][0][j]*wa0 + m[rt][1][j]*wa1;
        #pragma unroll
        for (int msk = 1; msk < 16; msk <<= 1) {
            #pragma unroll
            for (int rt = 0; rt < 4; ++rt)
                #pragma unroll
                for (int j = 0; j < 4; ++j)
                    p[rt][j] += __shfl_xor(p[rt][j], msk);
        }
        if (lr == 0) {
            #pragma unroll
            for (int rt = 0; rt < 4; ++rt)
                #pragma unroll
                for (int j = 0; j < 4; ++j)
                    sAP[w*64 + rt*16 + 4*lh + j] = p[rt][j];
        }
    }
    __syncthreads();                                    // bar6
    if (tid < EPB)
        sAttv[tid] = sigf(sAP[tid] + sAP[64+tid] + sAP[128+tid] + sAP[192+tid] + batt[0]);
    __syncthreads();                                    // bar7

    // ---- gated aggregate -> aggH/aggL ----------------------------------
    #pragma unroll
    for (int rt = 0; rt < 4; ++rt) {
        float s0 = 0.0f, s1 = 0.0f;
        #pragma unroll
        for (int j = 0; j < 4; ++j) {
            const float av = sAttv[rt*16 + 4*lh + j];
            s0 += m[rt][0][j]*av;
            s1 += m[rt][1][j]*av;
        }
        s0 += __shfl_xor(s0, 16);
        s1 += __shfl_xor(s1, 16);
        if ((lh & 1) == 0) {
            const int node = node0 + 2*rt + (lh >> 1);
            wragg(aggH, aggL, (size_t)node*HID + colB0, s0*0.2f);
            wragg(aggH, aggL, (size_t)node*HID + colB1, s1*0.2f);
        }
    }
}

// ---------------------------------------------------------------- node (MFMA, 32 nodes/block)
__global__ __launch_bounds__(256, 6) void node_k(
    float* __restrict__ hh, u16* __restrict__ hhH, u16* __restrict__ hhL,
    const u16* __restrict__ aggH, const u16* __restrict__ aggL,
    const u16* __restrict__ B1H, const u16* __restrict__ B1L,
    const u16* __restrict__ B2H, const u16* __restrict__ B2L,
    const float* __restrict__ bn1, const float* __restrict__ g2,
    const float* __restrict__ bt2, const float* __restrict__ bn2)
{
    __shared__ __align__(16) char smem[16896];
    float* sMid = (float*)smem;
    u16* sYH = (u16*)smem;
    u16* sYL = (u16*)(smem + 8192);

    const int tid = threadIdx.x;
    const int node0 = blockIdx.x * 32;
    const int w = tid >> 6, lane = tid & 63, lr = lane & 15, lh = lane >> 4;
    const int colB0 = w*32 + lr, colB1 = colB0 + 16;

    const u16* a1h0 = hhH  + (size_t)(node0+lr)*HID + lh*8;
    const u16* a1l0 = hhL  + (size_t)(node0+lr)*HID + lh*8;
    const u16* a2h0 = aggH + (size_t)(node0+lr)*HID + lh*8;
    const u16* a2l0 = aggL + (size_t)(node0+lr)*HID + lh*8;
    const u16* c1H0 = B1H + (size_t)colB0*256 + lh*8;
    const u16* c1H1 = B1H + (size_t)colB1*256 + lh*8;
    const u16* c1L0 = B1L + (size_t)colB0*256 + lh*8;
    const u16* c1L1 = B1L + (size_t)colB1*256 + lh*8;

    f32x4 acc00={0,0,0,0}, acc01={0,0,0,0}, acc10={0,0,0,0}, acc11={0,0,0,0};
    {
        bfx8 wh0 = *(const bfx8*)c1H0, wh1 = *(const bfx8*)c1H1;
        bfx8 wl0 = *(const bfx8*)c1L0, wl1 = *(const bfx8*)c1L1;
        #pragma unroll
        for (int s = 0; s < 8; ++s) {
            bfx8 nh0 = wh0, nh1 = wh1, nl0 = wl0, nl1 = wl1;
            if (s < 7) {
                nh0 = *(const bfx8*)(c1H0 + 32*(s+1)); nh1 = *(const bfx8*)(c1H1 + 32*(s+1));
                nl0 = *(const bfx8*)(c1L0 + 32*(s+1)); nl1 = *(const bfx8*)(c1L1 + 32*(s+1));
            }
            bfx8 ah0, ah1, al0, al1;
            if (s < 4) {
                ah0 = *(const bfx8*)(a1h0 + 32*s);            ah1 = *(const bfx8*)(a1h0 + 16*HID + 32*s);
                al0 = *(const bfx8*)(a1l0 + 32*s);            al1 = *(const bfx8*)(a1l0 + 16*HID + 32*s);
            } else {
                ah0 = *(const bfx8*)(a2h0 + 32*(s-4));        ah1 = *(const bfx8*)(a2h0 + 16*HID + 32*(s-4));
                al0 = *(const bfx8*)(a2l0 + 32*(s-4));        al1 = *(const bfx8*)(a2l0 + 16*HID + 32*(s-4));
            }
            acc00 = mfma3(ah0, al0, wh0, wl0, acc00);
            acc01 = mfma3(ah0, al0, wh1, wl1, acc01);
            acc10 = mfma3(ah1, al1, wh0, wl0, acc10);
            acc11 = mfma3(ah1, al1, wh1, wl1, acc11);
            wh0 = nh0; wh1 = nh1; wl0 = nl0; wl1 = nl1;
        }
    }
    {
        const float b10 = bn1[colB0], b11 = bn1[colB1];
        #pragma unroll
        for (int j = 0; j < 4; ++j) {
            const int r0 = 4*lh + j;
            sMid[r0*MIDSTR + colB0]      = acc00[j] + b10;
            sMid[r0*MIDSTR + colB1]      = acc01[j] + b11;
            sMid[(16+r0)*MIDSTR + colB0] = acc10[j] + b10;
            sMid[(16+r0)*MIDSTR + colB1] = acc11[j] + b11;
        }
    }
    __syncthreads();

    float y[16];
    const int eLN = tid >> 3, c0 = (tid & 7)*16;
    {
        const float* mrow = &sMid[eLN*MIDSTR + c0];
        float4 v0 = *(const float4*)&mrow[0];
        float4 v1 = *(const float4*)&mrow[4];
        float4 v2 = *(const float4*)&mrow[8];
        float4 v3 = *(const float4*)&mrow[12];
        float s = v0.x+v0.y+v0.z+v0.w + v1.x+v1.y+v1.z+v1.w
                + v2.x+v2.y+v2.z+v2.w + v3.x+v3.y+v3.z+v3.w;
        float q = v0.x*v0.x+v0.y*v0.y+v0.z*v0.z+v0.w*v0.w
                + v1.x*v1.x+v1.y*v1.y+v1.z*v1.z+v1.w*v1.w
                + v2.x*v2.x+v2.y*v2.y+v2.z*v2.z+v2.w*v2.w
                + v3.x*v3.x+v3.y*v3.y+v3.z*v3.z+v3.w*v3.w;
        #pragma unroll
        for (int m = 4; m >= 1; m >>= 1) { s += __shfl_xor(s, m); q += __shfl_xor(q, m); }
        float mu  = s * (1.0f/HID);
        float var = q * (1.0f/HID) - mu*mu;
        float inv = rsqrtf(var + 1e-5f);
        const float4 G0 = *(const float4*)&g2[c0+0],  G1v = *(const float4*)&g2[c0+4];
        const float4 G2 = *(const float4*)&g2[c0+8],  G3 = *(const float4*)&g2[c0+12];
        const float4 B0 = *(const float4*)&bt2[c0+0], B1 = *(const float4*)&bt2[c0+4];
        const float4 B2 = *(const float4*)&bt2[c0+8], B3 = *(const float4*)&bt2[c0+12];
        y[0]=siluf(fmaf((v0.x-mu)*inv,G0.x,B0.x));  y[1]=siluf(fmaf((v0.y-mu)*inv,G0.y,B0.y));
        y[2]=siluf(fmaf((v0.z-mu)*inv,G0.z,B0.z));  y[3]=siluf(fmaf((v0.w-mu)*inv,G0.w,B0.w));
        y[4]=siluf(fmaf((v1.x-mu)*inv,G1v.x,B1.x)); y[5]=siluf(fmaf((v1.y-mu)*inv,G1v.y,B1.y));
        y[6]=siluf(fmaf((v1.z-mu)*inv,G1v.z,B1.z)); y[7]=siluf(fmaf((v1.w-mu)*inv,G1v.w,B1.w));
        y[8]=siluf(fmaf((v2.x-mu)*inv,G2.x,B2.x));  y[9]=siluf(fmaf((v2.y-mu)*inv,G2.y,B2.y));
        y[10]=siluf(fmaf((v2.z-mu)*inv,G2.z,B2.z)); y[11]=siluf(fmaf((v2.w-mu)*inv,G2.w,B2.w));
        y[12]=siluf(fmaf((v3.x-mu)*inv,G3.x,B3.x)); y[13]=siluf(fmaf((v3.y-mu)*inv,G3.y,B3.y));
        y[14]=siluf(fmaf((v3.z-mu)*inv,G3.z,B3.z)); y[15]=siluf(fmaf((v3.w-mu)*inv,G3.w,B3.w));
    }
    __syncthreads();
    {
        U8 ha, hb2, la, lb2;
        #pragma unroll
        for (int j = 0; j < 8; ++j) {
            u16 t0 = bf16_rn(y[j]);   ha.a[j]  = t0; la.a[j]  = bf16_rn(y[j]   - bf16_tof(t0));
            u16 t1 = bf16_rn(y[8+j]); hb2.a[j] = t1; lb2.a[j] = bf16_rn(y[8+j] - bf16_tof(t1));
        }
        const int cA = (2*(tid & 7))     ^ (eLN & 15);
        const int cB = (2*(tid & 7) + 1) ^ (eLN & 15);
        *(bfx8*)&sYH[eLN*128 + (cA << 3)] = ha.v;
        *(bfx8*)&sYH[eLN*128 + (cB << 3)] = hb2.v;
        *(bfx8*)&sYL[eLN*128 + (cA << 3)] = la.v;
        *(bfx8*)&sYL[eLN*128 + (cB << 3)] = lb2.v;
    }
    __syncthreads();

    f32x4 d00={0,0,0,0}, d01={0,0,0,0}, d10={0,0,0,0}, d11={0,0,0,0};
    {
        const u16* c2H0 = B2H + (size_t)colB0*HID + lh*8;
        const u16* c2H1 = B2H + (size_t)colB1*HID + lh*8;
        const u16* c2L0 = B2L + (size_t)colB0*HID + lh*8;
        const u16* c2L1 = B2L + (size_t)colB1*HID + lh*8;
        bfx8 wh0 = *(const bfx8*)c2H0, wh1 = *(const bfx8*)c2H1;
        bfx8 wl0 = *(const bfx8*)c2L0, wl1 = *(const bfx8*)c2L1;
        #pragma unroll
        for (int s = 0; s < 4; ++s) {
            bfx8 nh0 = wh0, nh1 = wh1, nl0 = wl0, nl1 = wl1;
            if (s < 3) {
                nh0 = *(const bfx8*)(c2H0 + 32*(s+1)); nh1 = *(const bfx8*)(c2H1 + 32*(s+1));
                nl0 = *(const bfx8*)(c2L0 + 32*(s+1)); nl1 = *(const bfx8*)(c2L1 + 32*(s+1));
            }
            const int c4 = s*4 + lh;
            const int i0 = lr*128 + ((c4 ^ lr) << 3);
            const int i1 = (16+lr)*128 + ((c4 ^ lr) << 3);
            bfx8 ah0 = *(const bfx8*)&sYH[i0], ah1 = *(const bfx8*)&sYH[i1];
            bfx8 al0 = *(const bfx8*)&sYL[i0], al1 = *(const bfx8*)&sYL[i1];
            d00 = mfma3(ah0, al0, wh0, wl0, d00);
            d01 = mfma3(ah0, al0, wh1, wl1, d01);
            d10 = mfma3(ah1, al1, wh0, wl0, d10);
            d11 = mfma3(ah1, al1, wh1, wl1, d11);
            wh0 = nh0; wh1 = nh1; wl0 = nl0; wl1 = nl1;
        }
    }

    {
        const float b20 = bn2[colB0], b21 = bn2[colB1];
        #pragma unroll
        for (int j = 0; j < 4; ++j) {
            const int r0 = 4*lh + j, r1 = 16 + 4*lh + j;
            const size_t i00 = (size_t)(node0+r0)*HID + colB0;
            const size_t i01 = (size_t)(node0+r0)*HID + colB1;
            const size_t i10 = (size_t)(node0+r1)*HID + colB0;
            const size_t i11 = (size_t)(node0+r1)*HID + colB1;
            float v00 = hh[i00] + d00[j] + b20;
            float v01 = hh[i01] + d01[j] + b21;
            float v10 = hh[i10] + d10[j] + b20;
            float v11 = hh[i11] + d11[j] + b21;
            hh[i00] = v00; hh[i01] = v01; hh[i10] = v10; hh[i11] = v11;
            u16 h00 = bf16_rn(v00); hhH[i00] = h00; hhL[i00] = bf16_rn(v00 - bf16_tof(h00));
            u16 h01 = bf16_rn(v01); hhH[i01] = h01; hhL[i01] = bf16_rn(v01 - bf16_tof(h01));
            u16 h10 = bf16_rn(v10); hhH[i10] = h10; hhL[i10] = bf16_rn(v10 - bf16_tof(h10));
            u16 h11 = bf16_rn(v11); hhH[i11] = h11; hhL[i11] = bf16_rn(v11 - bf16_tof(h11));
        }
    }
}

// ---------------------------------------------------------------- output head
__global__ __launch_bounds__(HID) void out_k(
    const float* __restrict__ hh, const float* __restrict__ Woe,
    const float* __restrict__ boe, const float* __restrict__ Wf,
    const float* __restrict__ bf, float* __restrict__ out)
{
    __shared__ float sH[HID];
    const int lig = blockIdx.x, tid = threadIdx.x;
    float s = 0.0f;
    const float* base = hh + (size_t)lig*KAT*HID + tid;
    #pragma unroll 8
    for (int a = 0; a < KAT; ++a) s += base[a*HID];
    sH[tid] = s * (1.0f/KAT);
    __syncthreads();

    float contrib = 0.0f;
    if (tid < OUTF) {
        float p = boe[tid];
        #pragma unroll 4
        for (int i = 0; i < HID; ++i)
            p = fmaf(sH[i], Woe[i*OUTF + tid], p);
        contrib = p * Wf[tid];
    }
    #pragma unroll
    for (int m = 1; m < 64; m <<= 1) contrib += __shfl_xor(contrib, m);
    if (tid == 0) out[lig] = contrib + bf[0];
}

// ---------------------------------------------------------------- launch
extern "C" void kernel_launch(void* const* d_in, const int* in_sizes, int n_in,
                              void* d_out, int out_size, void* d_ws, size_t ws_size,
                              hipStream_t stream)
{
    (void)in_sizes; (void)n_in; (void)out_size; (void)ws_size;
    const float* x    = (const float*)d_in[0];
    const float* h    = (const float*)d_in[1];
    const int*   t    = (const int*)d_in[2];
    const int*   edges= (const int*)d_in[3];
    const int*   tb   = (const int*)d_in[4];
    const float* temb = (const float*)d_in[8];
    const float* Win  = (const float*)d_in[9];
    const float* bin  = (const float*)d_in[10];
    const float* We1  = (const float*)d_in[11];
    const float* be1  = (const float*)d_in[12];
    const float* g1   = (const float*)d_in[13];
    const float* bt1  = (const float*)d_in[14];
    const float* We2  = (const float*)d_in[15];
    const float* be2  = (const float*)d_in[16];
    const float* Watt = (const float*)d_in[17];
    const float* batt = (const float*)d_in[18];
    const float* Wn1  = (const float*)d_in[19];
    const float* bn1  = (const float*)d_in[20];
    const float* g2   = (const float*)d_in[21];
    const float* bt2  = (const float*)d_in[22];
    const float* Wn2  = (const float*)d_in[23];
    const float* bn2  = (const float*)d_in[24];
    const float* Woe  = (const float*)d_in[25];
    const float* boe  = (const float*)d_in[26];
    const float* Wf   = (const float*)d_in[27];
    const float* bf   = (const float*)d_in[28];
    float* out = (float*)d_out;

    char* wsb = (char*)d_ws;
    float* hh  = (float*)(wsb);                        // 16 MB
    u16* hhH   = (u16*)(wsb + ((size_t)16<<20));       // 8 MB
    u16* hhL   = (u16*)(wsb + ((size_t)24<<20));       // 8 MB
    u16* aggH  = (u16*)(wsb + ((size_t)32<<20));       // 8 MB
    u16* aggL  = (u16*)(wsb + ((size_t)40<<20));       // 8 MB
    u16* tembH = (u16*)(wsb + ((size_t)48<<20));
    u16* tembL = tembH + PREP_TEMB;
    u16* W1TH  = tembL + PREP_TEMB;
    u16* W1TL  = W1TH + PREP_W1;
    u16* W2TH  = W1TL + PREP_W1;
    u16* W2TL  = W2TH + PREP_W2;
    u16* WN1TH = W2TL + PREP_W2;
    u16* WN1TL = WN1TH + PREP_WN1;
    u16* WN2TH = WN1TL + PREP_WN1;
    u16* WN2TL = WN2TH + PREP_WN2;

    prep_k<<<(PREP_TOT + 255)/256, 256, 0, stream>>>(
        temb, We1, We2, Wn1, Wn2,
        tembH, tembL, W1TH, W1TL, W2TH, W2TL, WN1TH, WN1TL, WN2TH, WN2TL);

    embed_k<<<NNODES/8, 256, 0, stream>>>(h, t, temb, Win, bin, hh, hhH, hhL);

    for (int l = 0; l < 4; ++l) {
        edge_k<<<NNODES/NPB, 256, 0, stream>>>(
            hhH, hhL, x, edges + NEDGES, tb, tembH, tembL,
            W1TH + (size_t)l*128*K1, W1TL + (size_t)l*128*K1,
            W2TH + (size_t)l*128*128, W2TL + (size_t)l*128*128,
            be1 + l*HID, g1 + l*HID, bt1 + l*HID, be2 + l*HID,
            Watt + l*HID, batt + l, aggH, aggL);
        node_k<<<NNODES/32, 256, 0, stream>>>(
            hh, hhH, hhL, aggH, aggL,
            WN1TH + (size_t)l*128*256, WN1TL + (size_t)l*128*256,
            WN2TH + (size_t)l*128*128, WN2TL + (size_t)l*128*128,
            bn1 + l*HID, g2 + l*HID, bt2 + l*HID, bn2 + l*HID);
    }
    out_k<<<NLIG, HID, 0, stream>>>(hh, Woe, boe, Wf, bf, out);
}